// Round 1
// baseline (2997.899 us; speedup 1.0000x reference)
//
#include <hip/hip_runtime.h>
#include <math.h>

#define TM 64
#define TN 64
#define KC 16

__device__ __forceinline__ float sigf(float x) { return 1.0f / (1.0f + __expf(-x)); }

// ---------------------------------------------------------------------------
// Fused GRU step: h_out = GRUCell(x_t, h_in)
// gates (torch order r,z,n):
//   gi = x_t @ W_ih + b_ih ; gh = h @ W_hh + b_hh
//   r = sig(gi_r+gh_r); z = sig(gi_z+gh_z); n = tanh(gi_n + r*gh_n)
//   h' = (1-z)*n + z*h
// One block computes a 64(node) x 64(hidden col) tile; both K-loops fused.
// ---------------------------------------------------------------------------
__global__ __launch_bounds__(256)
void gru_step_kernel(const float* __restrict__ x_seq, int t, int L, int I,
                     const float* __restrict__ h_in, float* __restrict__ h_out,
                     const float* __restrict__ W_ih, const float* __restrict__ W_hh,
                     const float* __restrict__ b_ih, const float* __restrict__ b_hh,
                     int H)
{
    const int m0 = blockIdx.x * TM;
    const int j0 = blockIdx.y * TN;
    const int tid = (int)threadIdx.x;
    const int ty = tid >> 4, tx = tid & 15;

    __shared__ float As[KC][TM];       // transposed A chunk
    __shared__ float Bs[3][KC][TN];    // r,z,n weight tiles

    float accr[4][4] = {{0.f}}, accz[4][4] = {{0.f}};
    float accn[4][4] = {{0.f}}, acch[4][4] = {{0.f}};

    const int ldx = L * I;
    const int ldw = 3 * H;

    // ---- pass 1: x_t @ W_ih (K = I) -> accr, accz, accn
    for (int k0 = 0; k0 < I; k0 += KC) {
        {
            const int i = tid >> 2, q4 = (tid & 3) * 4;
            const float4 v = *reinterpret_cast<const float4*>(
                x_seq + (size_t)(m0 + i) * ldx + (size_t)t * I + k0 + q4);
            As[q4 + 0][i] = v.x; As[q4 + 1][i] = v.y;
            As[q4 + 2][i] = v.z; As[q4 + 3][i] = v.w;
        }
        {
            const int j = tid & 63, kq = tid >> 6;
            #pragma unroll
            for (int g = 0; g < 3; ++g)
                #pragma unroll
                for (int q = 0; q < 4; ++q) {
                    const int k = kq * 4 + q;
                    Bs[g][k][j] = W_ih[(size_t)(k0 + k) * ldw + g * H + j0 + j];
                }
        }
        __syncthreads();
        #pragma unroll
        for (int k = 0; k < KC; ++k) {
            float a[4], br[4], bz[4], bn[4];
            #pragma unroll
            for (int r = 0; r < 4; ++r) a[r] = As[k][ty * 4 + r];
            #pragma unroll
            for (int c = 0; c < 4; ++c) {
                br[c] = Bs[0][k][tx * 4 + c];
                bz[c] = Bs[1][k][tx * 4 + c];
                bn[c] = Bs[2][k][tx * 4 + c];
            }
            #pragma unroll
            for (int r = 0; r < 4; ++r)
                #pragma unroll
                for (int c = 0; c < 4; ++c) {
                    accr[r][c] += a[r] * br[c];
                    accz[r][c] += a[r] * bz[c];
                    accn[r][c] += a[r] * bn[c];
                }
        }
        __syncthreads();
    }

    // ---- pass 2: h @ W_hh (K = H) -> accr, accz (add), acch (= hn)
    for (int k0 = 0; k0 < H; k0 += KC) {
        {
            const int i = tid >> 2, q4 = (tid & 3) * 4;
            const float4 v = *reinterpret_cast<const float4*>(
                h_in + (size_t)(m0 + i) * H + k0 + q4);
            As[q4 + 0][i] = v.x; As[q4 + 1][i] = v.y;
            As[q4 + 2][i] = v.z; As[q4 + 3][i] = v.w;
        }
        {
            const int j = tid & 63, kq = tid >> 6;
            #pragma unroll
            for (int g = 0; g < 3; ++g)
                #pragma unroll
                for (int q = 0; q < 4; ++q) {
                    const int k = kq * 4 + q;
                    Bs[g][k][j] = W_hh[(size_t)(k0 + k) * ldw + g * H + j0 + j];
                }
        }
        __syncthreads();
        #pragma unroll
        for (int k = 0; k < KC; ++k) {
            float a[4], br[4], bz[4], bn[4];
            #pragma unroll
            for (int r = 0; r < 4; ++r) a[r] = As[k][ty * 4 + r];
            #pragma unroll
            for (int c = 0; c < 4; ++c) {
                br[c] = Bs[0][k][tx * 4 + c];
                bz[c] = Bs[1][k][tx * 4 + c];
                bn[c] = Bs[2][k][tx * 4 + c];
            }
            #pragma unroll
            for (int r = 0; r < 4; ++r)
                #pragma unroll
                for (int c = 0; c < 4; ++c) {
                    accr[r][c] += a[r] * br[c];
                    accz[r][c] += a[r] * bz[c];
                    acch[r][c] += a[r] * bn[c];
                }
        }
        __syncthreads();
    }

    // ---- epilogue: gates
    #pragma unroll
    for (int r = 0; r < 4; ++r) {
        const int m = m0 + ty * 4 + r;
        #pragma unroll
        for (int c = 0; c < 4; ++c) {
            const int j = j0 + tx * 4 + c;
            const float rg = sigf(accr[r][c] + b_ih[j] + b_hh[j]);
            const float zg = sigf(accz[r][c] + b_ih[H + j] + b_hh[H + j]);
            const float inn = accn[r][c] + b_ih[2 * H + j];
            const float hn  = acch[r][c] + b_hh[2 * H + j];
            const float ng = tanhf(inn + rg * hn);
            const float hp = h_in[(size_t)m * H + j];
            h_out[(size_t)m * H + j] = (1.f - zg) * ng + zg * hp;
        }
    }
}

// ---------------------------------------------------------------------------
// Generic tiled GEMM: C[M,N] = A[M,K] @ B[K,N] (+ bias[N] if bias != nullptr)
// M,N multiples of 64; K multiple of 16.
// ---------------------------------------------------------------------------
__global__ __launch_bounds__(256)
void gemm_bias_kernel(const float* __restrict__ A, const float* __restrict__ B,
                      const float* __restrict__ bias, float* __restrict__ C,
                      int M, int N, int K)
{
    const int m0 = blockIdx.x * TM;
    const int j0 = blockIdx.y * TN;
    const int tid = (int)threadIdx.x;
    const int ty = tid >> 4, tx = tid & 15;

    __shared__ float As[KC][TM];
    __shared__ float Bs[KC][TN];

    float acc[4][4] = {{0.f}};

    for (int k0 = 0; k0 < K; k0 += KC) {
        {
            const int i = tid >> 2, q4 = (tid & 3) * 4;
            const float4 v = *reinterpret_cast<const float4*>(
                A + (size_t)(m0 + i) * K + k0 + q4);
            As[q4 + 0][i] = v.x; As[q4 + 1][i] = v.y;
            As[q4 + 2][i] = v.z; As[q4 + 3][i] = v.w;
        }
        {
            const int j = tid & 63, kq = tid >> 6;
            #pragma unroll
            for (int q = 0; q < 4; ++q) {
                const int k = kq * 4 + q;
                Bs[k][j] = B[(size_t)(k0 + k) * N + j0 + j];
            }
        }
        __syncthreads();
        #pragma unroll
        for (int k = 0; k < KC; ++k) {
            float a[4], b[4];
            #pragma unroll
            for (int r = 0; r < 4; ++r) a[r] = As[k][ty * 4 + r];
            #pragma unroll
            for (int c = 0; c < 4; ++c) b[c] = Bs[k][tx * 4 + c];
            #pragma unroll
            for (int r = 0; r < 4; ++r)
                #pragma unroll
                for (int c = 0; c < 4; ++c)
                    acc[r][c] += a[r] * b[c];
        }
        __syncthreads();
    }

    #pragma unroll
    for (int r = 0; r < 4; ++r) {
        const int m = m0 + ty * 4 + r;
        #pragma unroll
        for (int c = 0; c < 4; ++c) {
            const int j = j0 + tx * 4 + c;
            const float bv = bias ? bias[j] : 0.f;
            C[(size_t)m * N + j] = acc[r][c] + bv;
        }
    }
}

// ---------------------------------------------------------------------------
// Tree kernels
// ---------------------------------------------------------------------------

// hs[parent[ch]-pstart][j] += h[ch][j] for children ch in [cstart, cstart+count)
__global__ void hsum_accum_kernel(const float* __restrict__ h,
                                  const int* __restrict__ parent,
                                  int cstart, int pstart, int count, int H,
                                  float* __restrict__ hs)
{
    const int idx = blockIdx.x * blockDim.x + threadIdx.x;
    if (idx >= count * H) return;
    const int ci = idx / H, j = idx - ci * H;
    const int ch = cstart + ci;
    const int p = parent[ch] - pstart;
    atomicAdd(&hs[(size_t)p * H + j], h[(size_t)ch * H + j]);
}

// f = sig(hU + xf[parent]); fcs[parent-pstart] += f * c[ch]
__global__ void fc_accum_kernel(const float* __restrict__ hU,
                                const float* __restrict__ xg,
                                const float* __restrict__ c,
                                const int* __restrict__ parent,
                                int cstart, int pstart, int count, int H,
                                float* __restrict__ fcs)
{
    const int idx = blockIdx.x * blockDim.x + threadIdx.x;
    if (idx >= count * H) return;
    const int ci = idx / H, j = idx - ci * H;
    const int ch = cstart + ci;
    const int p = parent[ch];
    const float f = sigf(hU[(size_t)ci * H + j] + xg[(size_t)p * 4 * H + 3 * H + j]);
    atomicAdd(&fcs[(size_t)(p - pstart) * H + j], f * c[(size_t)ch * H + j]);
}

// c/h update for the `count` nodes at pstart..pstart+count
__global__ void level_update_kernel(const float* __restrict__ xg,
                                    const float* __restrict__ giou,
                                    const float* __restrict__ fcs,
                                    float* __restrict__ c, float* __restrict__ h,
                                    int pstart, int count, int H)
{
    const int idx = blockIdx.x * blockDim.x + threadIdx.x;
    if (idx >= count * H) return;
    const int pi = idx / H, j = idx - pi * H;
    const int p = pstart + pi;
    const size_t xb = (size_t)p * 4 * H;
    const size_t gb = (size_t)pi * 3 * H;
    const float ig = sigf(xg[xb + j] + giou[gb + j]);
    const float og = sigf(xg[xb + H + j] + giou[gb + H + j]);
    const float ug = tanhf(xg[xb + 2 * H + j] + giou[gb + 2 * H + j]);
    const float cn = ig * ug + fcs[(size_t)pi * H + j];
    c[(size_t)p * H + j] = cn;
    h[(size_t)p * H + j] = og * tanhf(cn);
}

// out[0][t][j] = c[root_ids[t]][j]; out[1][t][j] = h[root_ids[t]][j]
__global__ void gather_out_kernel(const float* __restrict__ c,
                                  const float* __restrict__ h,
                                  const int* __restrict__ root_ids,
                                  int nroot, int H, float* __restrict__ out)
{
    const int idx = blockIdx.x * blockDim.x + threadIdx.x;
    if (idx >= nroot * H) return;
    const int t = idx / H, j = idx - t * H;
    const int rid = root_ids[t];
    out[idx] = c[(size_t)rid * H + j];
    out[(size_t)nroot * H + idx] = h[(size_t)rid * H + j];
}

// ---------------------------------------------------------------------------
extern "C" void kernel_launch(void* const* d_in, const int* in_sizes, int n_in,
                              void* d_out, int out_size, void* d_ws, size_t ws_size,
                              hipStream_t stream)
{
    const float* x_seq = (const float*)d_in[0];
    const float* W_ih  = (const float*)d_in[1];
    const float* W_hh  = (const float*)d_in[2];
    const float* b_ih  = (const float*)d_in[3];
    const float* b_hh  = (const float*)d_in[4];
    const float* Wx    = (const float*)d_in[5];
    const float* bx    = (const float*)d_in[6];
    const float* U_iou = (const float*)d_in[7];
    const float* U_f   = (const float*)d_in[8];
    const int* parent  = (const int*)d_in[9];
    const int* root_ids = (const int*)d_in[11];

    // derive dims from sizes (structure fixed by setup_inputs)
    const int threeH = in_sizes[3];          // 3H = 1536
    const int H   = threeH / 3;              // 512
    const int I   = in_sizes[1] / threeH;    // 256
    const int N   = in_sizes[9];             // 8192
    const int L   = in_sizes[0] / (N * I);   // 8
    const int PER = in_sizes[11];            // 1024
    const int D   = N / PER;                 // 8

    // workspace carve-up (floats)
    float* hA   = (float*)d_ws;              // N*H   (GRU ping; later tree c)
    float* hB   = hA + (size_t)N * H;        // N*H   (GRU pong; later tree h)
    float* xg   = hB + (size_t)N * H;        // N*4H
    float* hs   = xg + (size_t)N * 4 * H;    // PER*H
    float* fcs  = hs + (size_t)PER * H;      // PER*H
    float* giou = fcs + (size_t)PER * H;     // PER*3H
    float* hU   = giou + (size_t)PER * 3 * H;// PER*H

    // ---- Phase 1: GRU over L steps
    hipMemsetAsync(hA, 0, (size_t)N * H * sizeof(float), stream);
    {
        dim3 grid(N / TM, H / TN);
        const float* hin = hA;
        float* hout = hB;
        for (int t = 0; t < L; ++t) {
            gru_step_kernel<<<grid, 256, 0, stream>>>(x_seq, t, L, I, hin, hout,
                                                      W_ih, W_hh, b_ih, b_hh, H);
            float* tmp = (float*)hin; hin = hout; hout = tmp;
        }
        // L=8 (even): final enc lives in hA
    }

    // ---- Phase 2: xg = enc @ Wx + bx
    {
        dim3 grid(N / TM, (4 * H) / TN);
        gemm_bias_kernel<<<grid, 256, 0, stream>>>(hA, Wx, bx, xg, N, 4 * H, H);
    }

    // ---- Phase 3: tree levels (deepest -> roots)
    float* cT = hA;   // reuse
    float* hT = hB;   // reuse
    hipMemsetAsync(cT, 0, (size_t)N * H * sizeof(float), stream);
    hipMemsetAsync(hT, 0, (size_t)N * H * sizeof(float), stream);

    const int PH = PER * H;
    const int pw_blocks = (PH + 255) / 256;

    for (int lvl = D - 1; lvl >= 0; --lvl) {
        const int pstart = lvl * PER;
        const int cstart = (lvl + 1) * PER;
        const bool has_children = (lvl < D - 1);

        // zero hs and fcs (contiguous)
        hipMemsetAsync(hs, 0, 2 * (size_t)PH * sizeof(float), stream);

        if (has_children) {
            hsum_accum_kernel<<<pw_blocks, 256, 0, stream>>>(hT, parent, cstart,
                                                             pstart, PER, H, hs);
        }
        // giou = hs @ U_iou   (hs==0 at deepest level -> giou==0, still correct)
        {
            dim3 grid(PER / TM, (3 * H) / TN);
            gemm_bias_kernel<<<grid, 256, 0, stream>>>(hs, U_iou, nullptr, giou,
                                                       PER, 3 * H, H);
        }
        if (has_children) {
            dim3 grid(PER / TM, H / TN);
            gemm_bias_kernel<<<grid, 256, 0, stream>>>(hT + (size_t)cstart * H, U_f,
                                                       nullptr, hU, PER, H, H);
            fc_accum_kernel<<<pw_blocks, 256, 0, stream>>>(hU, xg, cT, parent,
                                                           cstart, pstart, PER, H, fcs);
        }
        level_update_kernel<<<pw_blocks, 256, 0, stream>>>(xg, giou, fcs, cT, hT,
                                                           pstart, PER, H);
    }

    // ---- Phase 4: gather roots
    gather_out_kernel<<<pw_blocks, 256, 0, stream>>>(cT, hT, root_ids, PER, H,
                                                     (float*)d_out);
}

// Round 2
// 940.892 us; speedup vs baseline: 3.1862x; 3.1862x over previous
//
#include <hip/hip_runtime.h>
#include <math.h>

typedef short bf16x8 __attribute__((ext_vector_type(8)));
typedef float f32x4 __attribute__((ext_vector_type(4)));

__device__ __forceinline__ float sigf(float x) { return 1.0f / (1.0f + __expf(-x)); }

__device__ __forceinline__ unsigned short f2bf(float f) {
    union { float f; unsigned u; } v; v.f = f;
    unsigned r = (v.u + 0x7FFFu + ((v.u >> 16) & 1u)) >> 16;
    return (unsigned short)r;
}

// ---------------------------------------------------------------------------
// prep kernels
// ---------------------------------------------------------------------------
__global__ void cvt_f32_bf16(const float* __restrict__ src,
                             unsigned short* __restrict__ dst, int n)
{
    const int i = (blockIdx.x * blockDim.x + threadIdx.x) * 4;
    if (i >= n) return;
    const float4 v = *reinterpret_cast<const float4*>(src + i);
    ushort4 o;
    o.x = f2bf(v.x); o.y = f2bf(v.y); o.z = f2bf(v.z); o.w = f2bf(v.w);
    *reinterpret_cast<ushort4*>(dst + i) = o;
}

// dst[c][r] = bf16(src[r][c]); rows, cols multiples of 32
__global__ void transpose_cvt(const float* __restrict__ src,
                              unsigned short* __restrict__ dst,
                              int rows, int cols)
{
    __shared__ float tile[32][33];
    const int bc = blockIdx.x * 32, br = blockIdx.y * 32;
    const int tx = threadIdx.x, ty = threadIdx.y;  // block (32,8)
    #pragma unroll
    for (int i = 0; i < 32; i += 8)
        tile[ty + i][tx] = src[(size_t)(br + ty + i) * cols + bc + tx];
    __syncthreads();
    #pragma unroll
    for (int i = 0; i < 32; i += 8)
        dst[(size_t)(bc + ty + i) * rows + br + tx] = f2bf(tile[tx][ty + i]);
}

// ---------------------------------------------------------------------------
// Generic MFMA GEMM: C[M][N] (f32) = A[M][K](bf16) @ BT[N][K](bf16)^T (+bias)
// 128x128 tile, BK=32, 4 waves in 2x2, each wave 64x64 (4x4 16x16 frags).
// ---------------------------------------------------------------------------
__global__ __launch_bounds__(256)
void mfma_gemm(const unsigned short* __restrict__ A,
               const unsigned short* __restrict__ BT,
               const float* __restrict__ bias,
               float* __restrict__ C, int M, int N, int K)
{
    const int m0 = blockIdx.x * 128, n0 = blockIdx.y * 128;
    const int tid = (int)threadIdx.x, lane = tid & 63, wid = tid >> 6;
    const int wm = wid >> 1, wn = wid & 1;

    __shared__ unsigned short As[128][40];   // +16B pad per row
    __shared__ unsigned short Bs[128][40];

    f32x4 acc[4][4];
    #pragma unroll
    for (int i = 0; i < 4; ++i)
        #pragma unroll
        for (int j = 0; j < 4; ++j)
            acc[i][j] = (f32x4){0.f, 0.f, 0.f, 0.f};

    const int row = tid >> 1, cc = (tid & 1) * 16;
    const unsigned short* ap = A + (size_t)(m0 + row) * K + cc;
    const unsigned short* bp = BT + (size_t)(n0 + row) * K + cc;
    unsigned short* asw = &As[row][cc];
    unsigned short* bsw = &Bs[row][cc];

    int4 pa0 = *(const int4*)(ap),     pa1 = *(const int4*)(ap + 8);
    int4 pb0 = *(const int4*)(bp),     pb1 = *(const int4*)(bp + 8);

    const int nkt = K >> 5;
    const int fr = lane & 15, kg = lane >> 4;

    for (int kt = 0; kt < nkt; ++kt) {
        __syncthreads();
        *(int4*)asw = pa0; *(int4*)(asw + 8) = pa1;
        *(int4*)bsw = pb0; *(int4*)(bsw + 8) = pb1;
        __syncthreads();
        if (kt + 1 < nkt) {
            const int ko = (kt + 1) << 5;
            pa0 = *(const int4*)(ap + ko); pa1 = *(const int4*)(ap + ko + 8);
            pb0 = *(const int4*)(bp + ko); pb1 = *(const int4*)(bp + ko + 8);
        }
        bf16x8 af[4], bf[4];
        #pragma unroll
        for (int mi = 0; mi < 4; ++mi)
            af[mi] = *reinterpret_cast<const bf16x8*>(&As[wm * 64 + mi * 16 + fr][kg * 8]);
        #pragma unroll
        for (int ni = 0; ni < 4; ++ni)
            bf[ni] = *reinterpret_cast<const bf16x8*>(&Bs[wn * 64 + ni * 16 + fr][kg * 8]);
        #pragma unroll
        for (int mi = 0; mi < 4; ++mi)
            #pragma unroll
            for (int ni = 0; ni < 4; ++ni)
                acc[mi][ni] = __builtin_amdgcn_mfma_f32_16x16x32_bf16(
                    af[mi], bf[ni], acc[mi][ni], 0, 0, 0);
    }

    #pragma unroll
    for (int ni = 0; ni < 4; ++ni) {
        const int n = n0 + wn * 64 + ni * 16 + fr;
        const float bv = bias ? bias[n] : 0.f;
        #pragma unroll
        for (int mi = 0; mi < 4; ++mi) {
            #pragma unroll
            for (int r = 0; r < 4; ++r) {
                const int m = m0 + wm * 64 + mi * 16 + kg * 4 + r;
                C[(size_t)m * N + n] = acc[mi][ni][r] + bv;
            }
        }
    }
}

// ---------------------------------------------------------------------------
// Fused MFMA GRU step. Block: 128 nodes x 64 hidden cols; waves 2x2
// (each 64 rows x 32 cols). Pass 1: K over I with W_ihT; pass 2: K over H
// with W_hhT. acc sets: r, z (both passes), nx (pass1 n), nh (pass2 n).
// ---------------------------------------------------------------------------
__global__ __launch_bounds__(256)
void gru_mfma(const unsigned short* __restrict__ xb, int t, int LI, int I,
              const unsigned short* __restrict__ hbi,
              unsigned short* __restrict__ hbo,
              const unsigned short* __restrict__ WihT,
              const unsigned short* __restrict__ WhhT,
              const float* __restrict__ b_ih, const float* __restrict__ b_hh,
              float* __restrict__ hf, int H)
{
    const int m0 = blockIdx.x * 128, j0 = blockIdx.y * 64;
    const int tid = (int)threadIdx.x, lane = tid & 63, wid = tid >> 6;
    const int wm = wid >> 1, wn = wid & 1;

    __shared__ unsigned short As[128][40];
    __shared__ unsigned short Bs[3][64][40];

    f32x4 ar[4][2], az[4][2], an[4][2], ah[4][2];
    #pragma unroll
    for (int i = 0; i < 4; ++i)
        #pragma unroll
        for (int j = 0; j < 2; ++j) {
            ar[i][j] = (f32x4){0.f, 0.f, 0.f, 0.f};
            az[i][j] = (f32x4){0.f, 0.f, 0.f, 0.f};
            an[i][j] = (f32x4){0.f, 0.f, 0.f, 0.f};
            ah[i][j] = (f32x4){0.f, 0.f, 0.f, 0.f};
        }

    const int arow = tid >> 1, ac = (tid & 1) * 16;
    unsigned short* asw = &As[arow][ac];
    const int brow = tid >> 2, bc = (tid & 3) * 8;
    unsigned short* bsw0 = &Bs[0][brow][bc];
    unsigned short* bsw1 = &Bs[1][brow][bc];
    unsigned short* bsw2 = &Bs[2][brow][bc];

    const int nkt1 = I >> 5, nkt2 = H >> 5, nkt = nkt1 + nkt2;
    int4 pa0, pa1, pb0, pb1, pb2;

    auto loadA = [&](int kt) {
        const unsigned short* p;
        if (kt < nkt1)
            p = xb + (size_t)(m0 + arow) * LI + t * I + (kt << 5) + ac;
        else
            p = hbi + (size_t)(m0 + arow) * H + ((kt - nkt1) << 5) + ac;
        pa0 = *(const int4*)p; pa1 = *(const int4*)(p + 8);
    };
    auto loadB = [&](int kt) {
        if (kt < nkt1) {
            const unsigned short* base =
                WihT + (size_t)(j0 + brow) * I + (kt << 5) + bc;
            const size_t g = (size_t)H * I;
            pb0 = *(const int4*)(base);
            pb1 = *(const int4*)(base + g);
            pb2 = *(const int4*)(base + 2 * g);
        } else {
            const unsigned short* base =
                WhhT + (size_t)(j0 + brow) * H + ((kt - nkt1) << 5) + bc;
            const size_t g = (size_t)H * H;
            pb0 = *(const int4*)(base);
            pb1 = *(const int4*)(base + g);
            pb2 = *(const int4*)(base + 2 * g);
        }
    };

    loadA(0); loadB(0);
    const int fr = lane & 15, kg = lane >> 4;

    for (int kt = 0; kt < nkt; ++kt) {
        __syncthreads();
        *(int4*)asw = pa0; *(int4*)(asw + 8) = pa1;
        *(int4*)bsw0 = pb0; *(int4*)bsw1 = pb1; *(int4*)bsw2 = pb2;
        __syncthreads();
        if (kt + 1 < nkt) { loadA(kt + 1); loadB(kt + 1); }

        bf16x8 af[4], bfr[2], bfz[2], bfn[2];
        #pragma unroll
        for (int mi = 0; mi < 4; ++mi)
            af[mi] = *reinterpret_cast<const bf16x8*>(&As[wm * 64 + mi * 16 + fr][kg * 8]);
        #pragma unroll
        for (int ni = 0; ni < 2; ++ni) {
            bfr[ni] = *reinterpret_cast<const bf16x8*>(&Bs[0][wn * 32 + ni * 16 + fr][kg * 8]);
            bfz[ni] = *reinterpret_cast<const bf16x8*>(&Bs[1][wn * 32 + ni * 16 + fr][kg * 8]);
            bfn[ni] = *reinterpret_cast<const bf16x8*>(&Bs[2][wn * 32 + ni * 16 + fr][kg * 8]);
        }
        const bool p1 = (kt < nkt1);
        #pragma unroll
        for (int mi = 0; mi < 4; ++mi)
            #pragma unroll
            for (int ni = 0; ni < 2; ++ni) {
                ar[mi][ni] = __builtin_amdgcn_mfma_f32_16x16x32_bf16(af[mi], bfr[ni], ar[mi][ni], 0, 0, 0);
                az[mi][ni] = __builtin_amdgcn_mfma_f32_16x16x32_bf16(af[mi], bfz[ni], az[mi][ni], 0, 0, 0);
                if (p1)
                    an[mi][ni] = __builtin_amdgcn_mfma_f32_16x16x32_bf16(af[mi], bfn[ni], an[mi][ni], 0, 0, 0);
                else
                    ah[mi][ni] = __builtin_amdgcn_mfma_f32_16x16x32_bf16(af[mi], bfn[ni], ah[mi][ni], 0, 0, 0);
            }
    }

    #pragma unroll
    for (int ni = 0; ni < 2; ++ni) {
        const int j = j0 + wn * 32 + ni * 16 + fr;
        const float bir = b_ih[j],         bhr = b_hh[j];
        const float biz = b_ih[H + j],     bhz = b_hh[H + j];
        const float bin = b_ih[2 * H + j], bhn = b_hh[2 * H + j];
        #pragma unroll
        for (int mi = 0; mi < 4; ++mi) {
            #pragma unroll
            for (int r = 0; r < 4; ++r) {
                const int m = m0 + wm * 64 + mi * 16 + kg * 4 + r;
                const float rg = sigf(ar[mi][ni][r] + bir + bhr);
                const float zg = sigf(az[mi][ni][r] + biz + bhz);
                const float ng = tanhf(an[mi][ni][r] + bin + rg * (ah[mi][ni][r] + bhn));
                const size_t off = (size_t)m * H + j;
                const float hv = hf[off];
                const float o = (1.f - zg) * ng + zg * hv;
                hf[off] = o;
                hbo[off] = f2bf(o);
            }
        }
    }
}

// ---------------------------------------------------------------------------
// Tree kernels (pointwise)
// ---------------------------------------------------------------------------
__global__ void hsum_accum_kernel(const float* __restrict__ h,
                                  const int* __restrict__ parent,
                                  int cstart, int pstart, int count, int H,
                                  float* __restrict__ hs)
{
    const int idx = blockIdx.x * blockDim.x + threadIdx.x;
    if (idx >= count * H) return;
    const int ci = idx / H, j = idx - ci * H;
    const int ch = cstart + ci;
    const int p = parent[ch] - pstart;
    atomicAdd(&hs[(size_t)p * H + j], h[(size_t)ch * H + j]);
}

__global__ void fc_accum_kernel(const float* __restrict__ hU,
                                const float* __restrict__ xg,
                                const float* __restrict__ c,
                                const int* __restrict__ parent,
                                int cstart, int pstart, int count, int H,
                                float* __restrict__ fcs)
{
    const int idx = blockIdx.x * blockDim.x + threadIdx.x;
    if (idx >= count * H) return;
    const int ci = idx / H, j = idx - ci * H;
    const int ch = cstart + ci;
    const int p = parent[ch];
    const float f = sigf(hU[(size_t)ci * H + j] + xg[(size_t)p * 4 * H + 3 * H + j]);
    atomicAdd(&fcs[(size_t)(p - pstart) * H + j], f * c[(size_t)ch * H + j]);
}

__global__ void level_update_kernel(const float* __restrict__ xg,
                                    const float* __restrict__ giou,
                                    const float* __restrict__ fcs,
                                    float* __restrict__ c, float* __restrict__ h,
                                    unsigned short* __restrict__ hb,
                                    int pstart, int count, int H)
{
    const int idx = blockIdx.x * blockDim.x + threadIdx.x;
    if (idx >= count * H) return;
    const int pi = idx / H, j = idx - pi * H;
    const int p = pstart + pi;
    const size_t xb = (size_t)p * 4 * H;
    const size_t gb = (size_t)pi * 3 * H;
    const float ig = sigf(xg[xb + j] + giou[gb + j]);
    const float og = sigf(xg[xb + H + j] + giou[gb + H + j]);
    const float ug = tanhf(xg[xb + 2 * H + j] + giou[gb + 2 * H + j]);
    const float cn = ig * ug + fcs[(size_t)pi * H + j];
    const float hn = og * tanhf(cn);
    c[(size_t)p * H + j] = cn;
    h[(size_t)p * H + j] = hn;
    hb[(size_t)p * H + j] = f2bf(hn);
}

__global__ void gather_out_kernel(const float* __restrict__ c,
                                  const float* __restrict__ h,
                                  const int* __restrict__ root_ids,
                                  int nroot, int H, float* __restrict__ out)
{
    const int idx = blockIdx.x * blockDim.x + threadIdx.x;
    if (idx >= nroot * H) return;
    const int t = idx / H, j = idx - t * H;
    const int rid = root_ids[t];
    out[idx] = c[(size_t)rid * H + j];
    out[(size_t)nroot * H + idx] = h[(size_t)rid * H + j];
}

// ---------------------------------------------------------------------------
extern "C" void kernel_launch(void* const* d_in, const int* in_sizes, int n_in,
                              void* d_out, int out_size, void* d_ws, size_t ws_size,
                              hipStream_t stream)
{
    const float* x_seq = (const float*)d_in[0];
    const float* W_ih  = (const float*)d_in[1];
    const float* W_hh  = (const float*)d_in[2];
    const float* b_ih  = (const float*)d_in[3];
    const float* b_hh  = (const float*)d_in[4];
    const float* Wx    = (const float*)d_in[5];
    const float* bx    = (const float*)d_in[6];
    const float* U_iou = (const float*)d_in[7];
    const float* U_f   = (const float*)d_in[8];
    const int* parent  = (const int*)d_in[9];
    const int* root_ids = (const int*)d_in[11];

    const int threeH = in_sizes[3];          // 1536
    const int H   = threeH / 3;              // 512
    const int I   = in_sizes[1] / threeH;    // 256
    const int N   = in_sizes[9];             // 8192
    const int L   = in_sizes[0] / (N * I);   // 8
    const int PER = in_sizes[11];            // 1024
    const int D   = N / PER;                 // 8

    const size_t NH = (size_t)N * H;
    const size_t PH = (size_t)PER * H;

    // ---- workspace carve-up (xb aliases xg: xb dead before xg written) ----
    char* p = (char*)d_ws;
    const size_t zone_sz = ((size_t)N * 4 * H * 4 > (size_t)N * L * I * 2)
                         ? (size_t)N * 4 * H * 4 : (size_t)N * L * I * 2;
    unsigned short* xb = (unsigned short*)p;
    float* xg = (float*)p;                       p += zone_sz;
    float* hf = (float*)p;                       p += NH * 4;
    float* cT = (float*)p;                       p += NH * 4;
    unsigned short* hb0 = (unsigned short*)p;    p += NH * 2;
    unsigned short* hb1 = (unsigned short*)p;    p += NH * 2;
    unsigned short* WihT = (unsigned short*)p;   p += (size_t)threeH * I * 2;
    unsigned short* WhhT = (unsigned short*)p;   p += (size_t)threeH * H * 2;
    unsigned short* WxT  = (unsigned short*)p;   p += (size_t)4 * H * H * 2;
    unsigned short* UiouT = (unsigned short*)p;  p += (size_t)threeH * H * 2;
    unsigned short* UfT  = (unsigned short*)p;   p += (size_t)H * H * 2;
    float* hs  = (float*)p;                      p += PH * 4;
    float* fcs = (float*)p;                      p += PH * 4;   // contiguous after hs
    unsigned short* hsb = (unsigned short*)p;    p += PH * 2;
    float* giou = (float*)p;                     p += PH * 3 * 4;
    float* hU   = (float*)p;                     p += PH * 4;
    if ((size_t)(p - (char*)d_ws) > ws_size) return;  // loud failure, no corruption

    // ---- prep: conversions + weight transposes ----
    {
        const int n = N * L * I;
        cvt_f32_bf16<<<(n / 4 + 255) / 256, 256, 0, stream>>>(x_seq, xb, n);
        dim3 blk(32, 8);
        transpose_cvt<<<dim3(threeH / 32, I / 32), blk, 0, stream>>>(W_ih, WihT, I, threeH);
        transpose_cvt<<<dim3(threeH / 32, H / 32), blk, 0, stream>>>(W_hh, WhhT, H, threeH);
        transpose_cvt<<<dim3(4 * H / 32, H / 32), blk, 0, stream>>>(Wx, WxT, H, 4 * H);
        transpose_cvt<<<dim3(threeH / 32, H / 32), blk, 0, stream>>>(U_iou, UiouT, H, threeH);
        transpose_cvt<<<dim3(H / 32, H / 32), blk, 0, stream>>>(U_f, UfT, H, H);
    }

    hipMemsetAsync(hf, 0, NH * 4, stream);
    hipMemsetAsync(hb0, 0, NH * 2, stream);

    // ---- Phase 1: GRU over L steps ----
    {
        dim3 grid(N / 128, H / 64);
        for (int t = 0; t < L; ++t) {
            const unsigned short* hin = (t & 1) ? hb1 : hb0;
            unsigned short* hout = (t & 1) ? hb0 : hb1;
            gru_mfma<<<grid, 256, 0, stream>>>(xb, t, L * I, I, hin, hout,
                                               WihT, WhhT, b_ih, b_hh, hf, H);
        }
        // L even -> final enc bf16 in hb0, enc f32 in hf
    }

    // ---- Phase 2: xg = enc @ Wx + bx ----
    mfma_gemm<<<dim3(N / 128, 4 * H / 128), 256, 0, stream>>>(
        hb0, WxT, bx, xg, N, 4 * H, H);

    // ---- Phase 3: tree (deepest -> roots); cT/hf/hb1 write-before-read ----
    unsigned short* hTb = hb1;
    const int pw_blocks = (int)((PH + 255) / 256);

    for (int lvl = D - 1; lvl >= 0; --lvl) {
        const int pstart = lvl * PER;
        const int cstart = (lvl + 1) * PER;
        const bool has_children = (lvl < D - 1);

        hipMemsetAsync(hs, 0, 2 * PH * 4, stream);  // hs + fcs

        if (has_children)
            hsum_accum_kernel<<<pw_blocks, 256, 0, stream>>>(hf, parent, cstart,
                                                             pstart, PER, H, hs);
        cvt_f32_bf16<<<(int)(PH / 4 + 255) / 256, 256, 0, stream>>>(hs, hsb, (int)PH);
        mfma_gemm<<<dim3(PER / 128, threeH / 128), 256, 0, stream>>>(
            hsb, UiouT, nullptr, giou, PER, threeH, H);

        if (has_children) {
            mfma_gemm<<<dim3(PER / 128, H / 128), 256, 0, stream>>>(
                hTb + (size_t)cstart * H, UfT, nullptr, hU, PER, H, H);
            fc_accum_kernel<<<pw_blocks, 256, 0, stream>>>(hU, xg, cT, parent,
                                                           cstart, pstart, PER, H, fcs);
        }
        level_update_kernel<<<pw_blocks, 256, 0, stream>>>(xg, giou, fcs, cT, hf,
                                                           hTb, pstart, PER, H);
    }

    // ---- Phase 4: gather roots ----
    gather_out_kernel<<<pw_blocks, 256, 0, stream>>>(cT, hf, root_ids, PER, H,
                                                     (float*)d_out);
}

// Round 4
// 778.342 us; speedup vs baseline: 3.8516x; 1.2088x over previous
//
#include <hip/hip_runtime.h>
#include <math.h>

typedef short bf16x8 __attribute__((ext_vector_type(8)));
typedef float f32x4 __attribute__((ext_vector_type(4)));

__device__ __forceinline__ float sigf(float x) { return 1.0f / (1.0f + __expf(-x)); }

__device__ __forceinline__ unsigned short f2bf(float f) {
    union { float f; unsigned u; } v; v.f = f;
    unsigned r = (v.u + 0x7FFFu + ((v.u >> 16) & 1u)) >> 16;
    return (unsigned short)r;
}
__device__ __forceinline__ float bf2f(unsigned short u) {
    union { unsigned u; float f; } v; v.u = ((unsigned)u) << 16; return v.f;
}

// async global->LDS, 16B per lane; LDS dest = wave-uniform base + lane*16B.
// Lane i must therefore source the i-th 16-byte slice of the chunk.
__device__ __forceinline__ void gload16(const unsigned short* g, unsigned short* l) {
    __builtin_amdgcn_global_load_lds(
        (const __attribute__((address_space(1))) void*)g,
        (__attribute__((address_space(3))) void*)l, 16, 0, 0);
}

// ---------------------------------------------------------------------------
// prep kernels
// ---------------------------------------------------------------------------
__global__ void cvt_f32_bf16(const float* __restrict__ src,
                             unsigned short* __restrict__ dst, int n)
{
    const int i = (blockIdx.x * blockDim.x + threadIdx.x) * 4;
    if (i >= n) return;
    const float4 v = *reinterpret_cast<const float4*>(src + i);
    ushort4 o;
    o.x = f2bf(v.x); o.y = f2bf(v.y); o.z = f2bf(v.z); o.w = f2bf(v.w);
    *reinterpret_cast<ushort4*>(dst + i) = o;
}

// dst[c][r] = bf16(src[r][c]); rows, cols multiples of 32
__global__ void transpose_cvt(const float* __restrict__ src,
                              unsigned short* __restrict__ dst,
                              int rows, int cols)
{
    __shared__ float tile[32][33];
    const int bc = blockIdx.x * 32, br = blockIdx.y * 32;
    const int tx = threadIdx.x, ty = threadIdx.y;  // block (32,8)
    #pragma unroll
    for (int i = 0; i < 32; i += 8)
        tile[ty + i][tx] = src[(size_t)(br + ty + i) * cols + bc + tx];
    __syncthreads();
    #pragma unroll
    for (int i = 0; i < 32; i += 8)
        dst[(size_t)(bc + ty + i) * rows + br + tx] = f2bf(tile[tx][ty + i]);
}

// ---------------------------------------------------------------------------
// Fused MFMA GRU step, m97-style staging. Tile 128 rows x 64 hidden cols,
// 4 waves 2x2 (wave 64x32). K: 8 tiles of x@Wih then 16 tiles of h@Whh.
// LDS: A[128][32] @ ushort 0, B[3][64][32] @ ushort 4096 (20 KiB, linear).
// Each 1 KiB chunk = 16 rows x 32 ushorts; lane i owns bytes [16i,16i+16):
//   lrow = lane>>2, lcol = (lane&3)*8.
// ---------------------------------------------------------------------------
__global__ __launch_bounds__(256)
void gru_mfma(const unsigned short* __restrict__ xb, int t,
              const unsigned short* __restrict__ hbi,
              unsigned short* __restrict__ hbo,
              const unsigned short* __restrict__ WihT,
              const unsigned short* __restrict__ WhhT,
              const float* __restrict__ b_ih, const float* __restrict__ b_hh)
{
    constexpr int I = 256, H = 512, LI = 2048;
    const int m0 = blockIdx.x * 128, j0 = blockIdx.y * 64;
    const int tid = (int)threadIdx.x, lane = tid & 63, wid = tid >> 6;
    const int wm = wid >> 1, wn = wid & 1;
    const int fr = lane & 15, kg = lane >> 4;
    const int lrow = lane >> 2, lcol = (lane & 3) * 8;

    __shared__ unsigned short smem[10240];

    f32x4 ar[4][2], az[4][2], an[4][2], ah[4][2];
    #pragma unroll
    for (int i = 0; i < 4; ++i)
        #pragma unroll
        for (int j = 0; j < 2; ++j) {
            ar[i][j] = (f32x4){0.f, 0.f, 0.f, 0.f};
            az[i][j] = (f32x4){0.f, 0.f, 0.f, 0.f};
            an[i][j] = (f32x4){0.f, 0.f, 0.f, 0.f};
            ah[i][j] = (f32x4){0.f, 0.f, 0.f, 0.f};
        }

    constexpr int nkt1 = I / 32;          // 8
    constexpr int nkt = (I + H) / 32;     // 24

    for (int kt = 0; kt < nkt; ++kt) {
        const bool p1 = (kt < nkt1);
        const int k0 = p1 ? kt * 32 : (kt - nkt1) * 32;
        __syncthreads();                   // prev readers done
        #pragma unroll
        for (int q = 0; q < 5; ++q) {
            const int c = wid * 5 + q;     // 20 chunks of 1 KiB
            if (c < 8) {
                const int row = c * 16 + lrow;
                const unsigned short* g = p1
                    ? xb + (size_t)(m0 + row) * LI + t * I + k0 + lcol
                    : hbi + (size_t)(m0 + row) * H + k0 + lcol;
                gload16(g, &smem[c * 512]);
            } else {
                const int bc = c - 8, gi = bc >> 2;
                const int row = (bc & 3) * 16 + lrow;
                const unsigned short* g = p1
                    ? WihT + (size_t)(gi * H + j0 + row) * I + k0 + lcol
                    : WhhT + (size_t)(gi * H + j0 + row) * H + k0 + lcol;
                gload16(g, &smem[c * 512]);
            }
        }
        __syncthreads();                   // drains vmcnt -> data visible

        bf16x8 af[4], bfr[2], bfz[2], bfn[2];
        #pragma unroll
        for (int mi = 0; mi < 4; ++mi)
            af[mi] = *reinterpret_cast<const bf16x8*>(
                &smem[(wm * 64 + mi * 16 + fr) * 32 + kg * 8]);
        #pragma unroll
        for (int ni = 0; ni < 2; ++ni) {
            const int br = wn * 32 + ni * 16 + fr;
            bfr[ni] = *reinterpret_cast<const bf16x8*>(&smem[4096 + (br) * 32 + kg * 8]);
            bfz[ni] = *reinterpret_cast<const bf16x8*>(&smem[4096 + (64 + br) * 32 + kg * 8]);
            bfn[ni] = *reinterpret_cast<const bf16x8*>(&smem[4096 + (128 + br) * 32 + kg * 8]);
        }
        #pragma unroll
        for (int mi = 0; mi < 4; ++mi)
            #pragma unroll
            for (int ni = 0; ni < 2; ++ni) {
                ar[mi][ni] = __builtin_amdgcn_mfma_f32_16x16x32_bf16(af[mi], bfr[ni], ar[mi][ni], 0, 0, 0);
                az[mi][ni] = __builtin_amdgcn_mfma_f32_16x16x32_bf16(af[mi], bfz[ni], az[mi][ni], 0, 0, 0);
                if (p1)
                    an[mi][ni] = __builtin_amdgcn_mfma_f32_16x16x32_bf16(af[mi], bfn[ni], an[mi][ni], 0, 0, 0);
                else
                    ah[mi][ni] = __builtin_amdgcn_mfma_f32_16x16x32_bf16(af[mi], bfn[ni], ah[mi][ni], 0, 0, 0);
            }
    }

    #pragma unroll
    for (int ni = 0; ni < 2; ++ni) {
        const int j = j0 + wn * 32 + ni * 16 + fr;
        const float bir = b_ih[j],         bhr = b_hh[j];
        const float biz = b_ih[H + j],     bhz = b_hh[H + j];
        const float bin = b_ih[2 * H + j], bhn = b_hh[2 * H + j];
        #pragma unroll
        for (int mi = 0; mi < 4; ++mi) {
            #pragma unroll
            for (int r = 0; r < 4; ++r) {
                const int m = m0 + wm * 64 + mi * 16 + kg * 4 + r;
                const float rg = sigf(ar[mi][ni][r] + bir + bhr);
                const float zg = sigf(az[mi][ni][r] + biz + bhz);
                const float ng = tanhf(an[mi][ni][r] + bin + rg * (ah[mi][ni][r] + bhn));
                const size_t off = (size_t)m * H + j;
                const float hv = bf2f(hbi[off]);
                hbo[off] = f2bf((1.f - zg) * ng + zg * hv);
            }
        }
    }
}

// ---------------------------------------------------------------------------
// m97-style GEMM: C[M][N](f32) = A[M][K](bf16) @ BT[N][K]^T (+bias). 128x128.
// ---------------------------------------------------------------------------
__global__ __launch_bounds__(256)
void mfma_gemm128(const unsigned short* __restrict__ A,
                  const unsigned short* __restrict__ BT,
                  const float* __restrict__ bias,
                  float* __restrict__ C, int M, int N, int K)
{
    const int m0 = blockIdx.x * 128, n0 = blockIdx.y * 128;
    const int tid = (int)threadIdx.x, lane = tid & 63, wid = tid >> 6;
    const int wm = wid >> 1, wn = wid & 1;
    const int fr = lane & 15, kg = lane >> 4;
    const int lrow = lane >> 2, lcol = (lane & 3) * 8;

    __shared__ unsigned short smem[8192];

    f32x4 acc[4][4];
    #pragma unroll
    for (int i = 0; i < 4; ++i)
        #pragma unroll
        for (int j = 0; j < 4; ++j)
            acc[i][j] = (f32x4){0.f, 0.f, 0.f, 0.f};

    const int nkt = K >> 5;
    for (int kt = 0; kt < nkt; ++kt) {
        const int k0 = kt * 32;
        __syncthreads();
        #pragma unroll
        for (int q = 0; q < 4; ++q) {
            const int c = wid * 4 + q;
            const unsigned short* g = (c < 8)
                ? A + (size_t)(m0 + c * 16 + lrow) * K + k0 + lcol
                : BT + (size_t)(n0 + (c - 8) * 16 + lrow) * K + k0 + lcol;
            gload16(g, &smem[c * 512]);
        }
        __syncthreads();

        bf16x8 af[4], bf[4];
        #pragma unroll
        for (int mi = 0; mi < 4; ++mi)
            af[mi] = *reinterpret_cast<const bf16x8*>(
                &smem[(wm * 64 + mi * 16 + fr) * 32 + kg * 8]);
        #pragma unroll
        for (int ni = 0; ni < 4; ++ni)
            bf[ni] = *reinterpret_cast<const bf16x8*>(
                &smem[4096 + (wn * 64 + ni * 16 + fr) * 32 + kg * 8]);
        #pragma unroll
        for (int mi = 0; mi < 4; ++mi)
            #pragma unroll
            for (int ni = 0; ni < 4; ++ni)
                acc[mi][ni] = __builtin_amdgcn_mfma_f32_16x16x32_bf16(
                    af[mi], bf[ni], acc[mi][ni], 0, 0, 0);
    }

    #pragma unroll
    for (int ni = 0; ni < 4; ++ni) {
        const int n = n0 + wn * 64 + ni * 16 + fr;
        const float bv = bias ? bias[n] : 0.f;
        #pragma unroll
        for (int mi = 0; mi < 4; ++mi)
            #pragma unroll
            for (int r = 0; r < 4; ++r) {
                const int m = m0 + wm * 64 + mi * 16 + kg * 4 + r;
                C[(size_t)m * N + n] = acc[mi][ni][r] + bv;
            }
    }
}

// ---------------------------------------------------------------------------
// Tree level mega-GEMM: per child row c, G = h_c @ [U_iou | U_f]  ([512]->[2048]).
// Epilogue: cols <1536 -> atomicAdd giou[parent]; cols >=1536 ->
// f=sig(G+xf[parent]) ; atomicAdd fcs[parent] += f*c_child. Tile 64x128.
// ---------------------------------------------------------------------------
__global__ __launch_bounds__(256)
void tree_gemm(const unsigned short* __restrict__ hTb,
               const unsigned short* __restrict__ UcombT,  // [2048][512]
               const float* __restrict__ xg,               // [N][2048]
               const float* __restrict__ cT,               // [N][512]
               const int* __restrict__ parent,
               int cstart, int pstart,
               float* __restrict__ giou,                   // [PER][1536]
               float* __restrict__ fcs)                    // [PER][512]
{
    constexpr int H = 512, N4H = 2048, G3H = 1536;
    const int m0 = blockIdx.x * 64, n0 = blockIdx.y * 128;
    const int tid = (int)threadIdx.x, lane = tid & 63, wid = tid >> 6;
    const int wm = wid >> 1, wn = wid & 1;
    const int fr = lane & 15, kg = lane >> 4;
    const int lrow = lane >> 2, lcol = (lane & 3) * 8;

    __shared__ unsigned short smem[6144];  // A [64][32], B [128][32]

    f32x4 acc[2][4];
    #pragma unroll
    for (int i = 0; i < 2; ++i)
        #pragma unroll
        for (int j = 0; j < 4; ++j)
            acc[i][j] = (f32x4){0.f, 0.f, 0.f, 0.f};

    constexpr int nkt = H / 32;  // 16
    for (int kt = 0; kt < nkt; ++kt) {
        const int k0 = kt * 32;
        __syncthreads();
        #pragma unroll
        for (int q = 0; q < 3; ++q) {
            const int c = wid * 3 + q;   // 12 chunks
            const unsigned short* g = (c < 4)
                ? hTb + (size_t)(cstart + m0 + c * 16 + lrow) * H + k0 + lcol
                : UcombT + (size_t)(n0 + (c - 4) * 16 + lrow) * H + k0 + lcol;
            gload16(g, &smem[c * 512]);
        }
        __syncthreads();

        bf16x8 af[2], bf[4];
        #pragma unroll
        for (int mi = 0; mi < 2; ++mi)
            af[mi] = *reinterpret_cast<const bf16x8*>(
                &smem[(wm * 32 + mi * 16 + fr) * 32 + kg * 8]);
        #pragma unroll
        for (int ni = 0; ni < 4; ++ni)
            bf[ni] = *reinterpret_cast<const bf16x8*>(
                &smem[2048 + (wn * 64 + ni * 16 + fr) * 32 + kg * 8]);
        #pragma unroll
        for (int mi = 0; mi < 2; ++mi)
            #pragma unroll
            for (int ni = 0; ni < 4; ++ni)
                acc[mi][ni] = __builtin_amdgcn_mfma_f32_16x16x32_bf16(
                    af[mi], bf[ni], acc[mi][ni], 0, 0, 0);
    }

    if (n0 < G3H) {
        #pragma unroll
        for (int mi = 0; mi < 2; ++mi)
            #pragma unroll
            for (int r = 0; r < 4; ++r) {
                const int m = m0 + wm * 32 + mi * 16 + kg * 4 + r;
                const int p = parent[cstart + m] - pstart;
                #pragma unroll
                for (int ni = 0; ni < 4; ++ni) {
                    const int n = n0 + wn * 64 + ni * 16 + fr;
                    atomicAdd(&giou[(size_t)p * G3H + n], acc[mi][ni][r]);
                }
            }
    } else {
        #pragma unroll
        for (int mi = 0; mi < 2; ++mi)
            #pragma unroll
            for (int r = 0; r < 4; ++r) {
                const int m = m0 + wm * 32 + mi * 16 + kg * 4 + r;
                const int child = cstart + m;
                const int p = parent[child];
                #pragma unroll
                for (int ni = 0; ni < 4; ++ni) {
                    const int jf = n0 + wn * 64 + ni * 16 + fr - G3H;
                    const float f = sigf(acc[mi][ni][r] + xg[(size_t)p * N4H + G3H + jf]);
                    atomicAdd(&fcs[(size_t)(p - pstart) * H + jf],
                              f * cT[(size_t)child * H + jf]);
                }
            }
    }
}

// ---------------------------------------------------------------------------
__global__ void level_update(const float* __restrict__ xg,
                             const float* __restrict__ giou,
                             const float* __restrict__ fcs,
                             float* __restrict__ cT, float* __restrict__ hT,
                             unsigned short* __restrict__ hb, int pstart)
{
    constexpr int H = 512, N4H = 2048, G3H = 1536;
    const int idx = blockIdx.x * blockDim.x + threadIdx.x;  // PER*H exact
    const int pi = idx >> 9, j = idx & (H - 1);
    const int p = pstart + pi;
    const size_t xb4 = (size_t)p * N4H;
    const size_t gb = (size_t)pi * G3H;
    const float ig = sigf(xg[xb4 + j] + giou[gb + j]);
    const float og = sigf(xg[xb4 + H + j] + giou[gb + H + j]);
    const float ug = tanhf(xg[xb4 + 2 * H + j] + giou[gb + 2 * H + j]);
    const float cn = ig * ug + fcs[idx];
    const float hn = og * tanhf(cn);
    const size_t off = (size_t)p * H + j;
    cT[off] = cn;
    hT[off] = hn;
    hb[off] = f2bf(hn);
}

__global__ void gather_out_kernel(const float* __restrict__ c,
                                  const float* __restrict__ h,
                                  const int* __restrict__ root_ids,
                                  int nroot, float* __restrict__ out)
{
    constexpr int H = 512;
    const int idx = blockIdx.x * blockDim.x + threadIdx.x;  // nroot*H exact
    const int t = idx >> 9, j = idx & (H - 1);
    const int rid = root_ids[t];
    out[idx] = c[(size_t)rid * H + j];
    out[(size_t)nroot * H + idx] = h[(size_t)rid * H + j];
}

// ---------------------------------------------------------------------------
extern "C" void kernel_launch(void* const* d_in, const int* in_sizes, int n_in,
                              void* d_out, int out_size, void* d_ws, size_t ws_size,
                              hipStream_t stream)
{
    const float* x_seq = (const float*)d_in[0];
    const float* W_ih  = (const float*)d_in[1];
    const float* W_hh  = (const float*)d_in[2];
    const float* b_ih  = (const float*)d_in[3];
    const float* b_hh  = (const float*)d_in[4];
    const float* Wx    = (const float*)d_in[5];
    const float* bx    = (const float*)d_in[6];
    const float* U_iou = (const float*)d_in[7];
    const float* U_f   = (const float*)d_in[8];
    const int* parent  = (const int*)d_in[9];
    const int* root_ids = (const int*)d_in[11];

    const int threeH = in_sizes[3];          // 1536
    const int H   = threeH / 3;              // 512
    const int I   = in_sizes[1] / threeH;    // 256
    const int N   = in_sizes[9];             // 8192
    const int L   = in_sizes[0] / (N * I);   // 8
    const int PER = in_sizes[11];            // 1024
    const int D   = N / PER;                 // 8

    const size_t NH = (size_t)N * H;
    const size_t PH = (size_t)PER * H;

    // ---- workspace carve-up (xb aliases xg: xb dead before xg written) ----
    char* p = (char*)d_ws;
    const size_t zone_sz = ((size_t)N * 4 * H * 4 > (size_t)N * L * I * 2)
                         ? (size_t)N * 4 * H * 4 : (size_t)N * L * I * 2;
    unsigned short* xb = (unsigned short*)p;
    float* xg = (float*)p;                       p += zone_sz;
    unsigned short* hb0 = (unsigned short*)p;    p += NH * 2;
    unsigned short* hb1 = (unsigned short*)p;    p += NH * 2;
    float* cT = (float*)p;                       p += NH * 4;
    float* hT = (float*)p;                       p += NH * 4;
    unsigned short* WihT = (unsigned short*)p;   p += (size_t)threeH * I * 2;
    unsigned short* WhhT = (unsigned short*)p;   p += (size_t)threeH * H * 2;
    unsigned short* WxT  = (unsigned short*)p;   p += (size_t)4 * H * H * 2;
    unsigned short* UcombT = (unsigned short*)p; p += (size_t)4 * H * H * 2;
    float* giou = (float*)p;                     p += PH * 3 * 4;
    float* fcs  = (float*)p;                     p += PH * 4;   // adjacent to giou
    if ((size_t)(p - (char*)d_ws) > ws_size) return;

    // ---- prep ----
    {
        const int n = N * L * I;
        cvt_f32_bf16<<<(n / 4 + 255) / 256, 256, 0, stream>>>(x_seq, xb, n);
        dim3 blk(32, 8);
        transpose_cvt<<<dim3(threeH / 32, I / 32), blk, 0, stream>>>(W_ih, WihT, I, threeH);
        transpose_cvt<<<dim3(threeH / 32, H / 32), blk, 0, stream>>>(W_hh, WhhT, H, threeH);
        transpose_cvt<<<dim3(4 * H / 32, H / 32), blk, 0, stream>>>(Wx, WxT, H, 4 * H);
        transpose_cvt<<<dim3(threeH / 32, H / 32), blk, 0, stream>>>(U_iou, UcombT, H, threeH);
        transpose_cvt<<<dim3(H / 32, H / 32), blk, 0, stream>>>(
            U_f, UcombT + (size_t)threeH * H, H, H);
    }
    hipMemsetAsync(hb0, 0, NH * 2, stream);

    // ---- Phase 1: GRU (bf16 state ping-pong) ----
    {
        dim3 grid(N / 128, H / 64);
        for (int t = 0; t < L; ++t) {
            const unsigned short* hin = (t & 1) ? hb1 : hb0;
            unsigned short* hout = (t & 1) ? hb0 : hb1;
            gru_mfma<<<grid, 256, 0, stream>>>(xb, t, hin, hout,
                                               WihT, WhhT, b_ih, b_hh);
        }
        // L even -> enc bf16 in hb0
    }

    // ---- Phase 2: xg = enc @ Wx + bx ----
    mfma_gemm128<<<dim3(N / 128, 4 * H / 128), 256, 0, stream>>>(
        hb0, WxT, bx, xg, N, 4 * H, H);

    // ---- Phase 3: tree levels (deepest -> roots) ----
    unsigned short* hTb = hb1;  // tree h (bf16), free after GRU
    const int pw_blocks = (int)(PH / 256);

    for (int lvl = D - 1; lvl >= 0; --lvl) {
        const int pstart = lvl * PER;
        const int cstart = (lvl + 1) * PER;

        hipMemsetAsync(giou, 0, PH * 4 * 4, stream);  // giou + fcs (adjacent)

        if (lvl < D - 1)
            tree_gemm<<<dim3(PER / 64, (4 * H) / 128), 256, 0, stream>>>(
                hTb, UcombT, xg, cT, parent, cstart, pstart, giou, fcs);

        level_update<<<pw_blocks, 256, 0, stream>>>(xg, giou, fcs, cT, hT,
                                                    hTb, pstart);
    }

    // ---- Phase 4: gather roots ----
    gather_out_kernel<<<pw_blocks, 256, 0, stream>>>(cT, hT, root_ids, PER,
                                                     (float*)d_out);
}

// Round 5
// 629.362 us; speedup vs baseline: 4.7634x; 1.2367x over previous
//
#include <hip/hip_runtime.h>
#include <math.h>

typedef short bf16x8 __attribute__((ext_vector_type(8)));
typedef float f32x4 __attribute__((ext_vector_type(4)));

__device__ __forceinline__ float sigf(float x) { return 1.0f / (1.0f + __expf(-x)); }

__device__ __forceinline__ unsigned short f2bf(float f) {
    union { float f; unsigned u; } v; v.f = f;
    unsigned r = (v.u + 0x7FFFu + ((v.u >> 16) & 1u)) >> 16;
    return (unsigned short)r;
}
__device__ __forceinline__ float bf2f(unsigned short u) {
    union { unsigned u; float f; } v; v.u = ((unsigned)u) << 16; return v.f;
}

// async global->LDS, 16B per lane; LDS dest = wave-uniform base + lane*16B.
__device__ __forceinline__ void gload16(const unsigned short* g, unsigned short* l) {
    __builtin_amdgcn_global_load_lds(
        (const __attribute__((address_space(1))) void*)g,
        (__attribute__((address_space(3))) void*)l, 16, 0, 0);
}

// ---------------------------------------------------------------------------
// prep kernels
// ---------------------------------------------------------------------------
__global__ void cvt_f32_bf16(const float* __restrict__ src,
                             unsigned short* __restrict__ dst, int n)
{
    const int i = (blockIdx.x * blockDim.x + threadIdx.x) * 4;
    if (i >= n) return;
    const float4 v = *reinterpret_cast<const float4*>(src + i);
    ushort4 o;
    o.x = f2bf(v.x); o.y = f2bf(v.y); o.z = f2bf(v.z); o.w = f2bf(v.w);
    *reinterpret_cast<ushort4*>(dst + i) = o;
}

// dst[c][r] = bf16(src[r][c]); rows, cols multiples of 32
__global__ void transpose_cvt(const float* __restrict__ src,
                              unsigned short* __restrict__ dst,
                              int rows, int cols)
{
    __shared__ float tile[32][33];
    const int bc = blockIdx.x * 32, br = blockIdx.y * 32;
    const int tx = threadIdx.x, ty = threadIdx.y;  // block (32,8)
    #pragma unroll
    for (int i = 0; i < 32; i += 8)
        tile[ty + i][tx] = src[(size_t)(br + ty + i) * cols + bc + tx];
    __syncthreads();
    #pragma unroll
    for (int i = 0; i < 32; i += 8)
        dst[(size_t)(bc + ty + i) * rows + br + tx] = f2bf(tile[tx][ty + i]);
}

// ---------------------------------------------------------------------------
// Fused MFMA GRU step, double-buffered LDS, 1 barrier per K-tile.
// Tile 128 rows x 64 hidden cols; 4 waves 2x2 (wave 64x32).
// K: 8 tiles of x@Wih then 16 tiles of h@Whh.
// Per buffer: A[128][32] @ 0, B[3][64][32] @ 4096 (10240 ushorts).
// 1 KiB chunk = 16 rows x 32 ushorts; lane i owns bytes [16i,16i+16):
//   lrow = lane>>2, lcol = (lane&3)*8.
// ---------------------------------------------------------------------------
__global__ __launch_bounds__(256)
void gru_mfma(const unsigned short* __restrict__ xb, int t,
              const unsigned short* __restrict__ hbi,
              unsigned short* __restrict__ hbo,
              const unsigned short* __restrict__ WihT,
              const unsigned short* __restrict__ WhhT,
              const float* __restrict__ b_ih, const float* __restrict__ b_hh)
{
    constexpr int I = 256, H = 512, LI = 2048;
    const int m0 = blockIdx.x * 128, j0 = blockIdx.y * 64;
    const int tid = (int)threadIdx.x, lane = tid & 63, wid = tid >> 6;
    const int wm = wid >> 1, wn = wid & 1;
    const int fr = lane & 15, kg = lane >> 4;
    const int lrow = lane >> 2, lcol = (lane & 3) * 8;

    __shared__ unsigned short smem[2 * 10240];

    f32x4 ar[4][2], az[4][2], an[4][2], ah[4][2];
    #pragma unroll
    for (int i = 0; i < 4; ++i)
        #pragma unroll
        for (int j = 0; j < 2; ++j) {
            ar[i][j] = (f32x4){0.f, 0.f, 0.f, 0.f};
            az[i][j] = (f32x4){0.f, 0.f, 0.f, 0.f};
            an[i][j] = (f32x4){0.f, 0.f, 0.f, 0.f};
            ah[i][j] = (f32x4){0.f, 0.f, 0.f, 0.f};
        }

    constexpr int nkt1 = I / 32;          // 8
    constexpr int nkt = (I + H) / 32;     // 24

    auto stage = [&](int buf, int kt) {
        const bool s1 = (kt < nkt1);
        const int k0 = s1 ? kt * 32 : (kt - nkt1) * 32;
        unsigned short* base = &smem[buf * 10240];
        #pragma unroll
        for (int q = 0; q < 5; ++q) {
            const int c = wid * 5 + q;     // 20 chunks of 1 KiB
            if (c < 8) {
                const int row = c * 16 + lrow;
                const unsigned short* g = s1
                    ? xb + (size_t)(m0 + row) * LI + t * I + k0 + lcol
                    : hbi + (size_t)(m0 + row) * H + k0 + lcol;
                gload16(g, base + c * 512);
            } else {
                const int bc = c - 8, gi = bc >> 2;
                const int row = (bc & 3) * 16 + lrow;
                const unsigned short* g = s1
                    ? WihT + (size_t)(gi * H + j0 + row) * I + k0 + lcol
                    : WhhT + (size_t)(gi * H + j0 + row) * H + k0 + lcol;
                gload16(g, base + c * 512);
            }
        }
    };

    stage(0, 0);
    __syncthreads();                       // buf0 ready

    for (int kt = 0; kt < nkt; ++kt) {
        const int cur = kt & 1;
        if (kt + 1 < nkt) stage(cur ^ 1, kt + 1);   // async prefetch

        const unsigned short* sb = &smem[cur * 10240];
        bf16x8 af[4], bfr[2], bfz[2], bfn[2];
        #pragma unroll
        for (int mi = 0; mi < 4; ++mi)
            af[mi] = *reinterpret_cast<const bf16x8*>(
                &sb[(wm * 64 + mi * 16 + fr) * 32 + kg * 8]);
        #pragma unroll
        for (int ni = 0; ni < 2; ++ni) {
            const int br = wn * 32 + ni * 16 + fr;
            bfr[ni] = *reinterpret_cast<const bf16x8*>(&sb[4096 + (br) * 32 + kg * 8]);
            bfz[ni] = *reinterpret_cast<const bf16x8*>(&sb[4096 + (64 + br) * 32 + kg * 8]);
            bfn[ni] = *reinterpret_cast<const bf16x8*>(&sb[4096 + (128 + br) * 32 + kg * 8]);
        }
        const bool p1 = (kt < nkt1);
        #pragma unroll
        for (int mi = 0; mi < 4; ++mi)
            #pragma unroll
            for (int ni = 0; ni < 2; ++ni) {
                ar[mi][ni] = __builtin_amdgcn_mfma_f32_16x16x32_bf16(af[mi], bfr[ni], ar[mi][ni], 0, 0, 0);
                az[mi][ni] = __builtin_amdgcn_mfma_f32_16x16x32_bf16(af[mi], bfz[ni], az[mi][ni], 0, 0, 0);
                if (p1)
                    an[mi][ni] = __builtin_amdgcn_mfma_f32_16x16x32_bf16(af[mi], bfn[ni], an[mi][ni], 0, 0, 0);
                else
                    ah[mi][ni] = __builtin_amdgcn_mfma_f32_16x16x32_bf16(af[mi], bfn[ni], ah[mi][ni], 0, 0, 0);
            }
        __syncthreads();   // drains prefetch (post-compute) + read-done on cur
    }

    #pragma unroll
    for (int ni = 0; ni < 2; ++ni) {
        const int j = j0 + wn * 32 + ni * 16 + fr;
        const float bir = b_ih[j],         bhr = b_hh[j];
        const float biz = b_ih[H + j],     bhz = b_hh[H + j];
        const float bin = b_ih[2 * H + j], bhn = b_hh[2 * H + j];
        #pragma unroll
        for (int mi = 0; mi < 4; ++mi) {
            #pragma unroll
            for (int r = 0; r < 4; ++r) {
                const int m = m0 + wm * 64 + mi * 16 + kg * 4 + r;
                const float rg = sigf(ar[mi][ni][r] + bir + bhr);
                const float zg = sigf(az[mi][ni][r] + biz + bhz);
                const float ng = tanhf(an[mi][ni][r] + bin + rg * (ah[mi][ni][r] + bhn));
                const size_t off = (size_t)m * H + j;
                const float hv = bf2f(hbi[off]);
                hbo[off] = f2bf((1.f - zg) * ng + zg * hv);
            }
        }
    }
}

// ---------------------------------------------------------------------------
// m97-style GEMM, double-buffered: C[M][N](f32) = A(bf16) @ BT^T (+bias). 128x128.
// ---------------------------------------------------------------------------
__global__ __launch_bounds__(256)
void mfma_gemm128(const unsigned short* __restrict__ A,
                  const unsigned short* __restrict__ BT,
                  const float* __restrict__ bias,
                  float* __restrict__ C, int M, int N, int K)
{
    const int m0 = blockIdx.x * 128, n0 = blockIdx.y * 128;
    const int tid = (int)threadIdx.x, lane = tid & 63, wid = tid >> 6;
    const int wm = wid >> 1, wn = wid & 1;
    const int fr = lane & 15, kg = lane >> 4;
    const int lrow = lane >> 2, lcol = (lane & 3) * 8;

    __shared__ unsigned short smem[2 * 8192];

    f32x4 acc[4][4];
    #pragma unroll
    for (int i = 0; i < 4; ++i)
        #pragma unroll
        for (int j = 0; j < 4; ++j)
            acc[i][j] = (f32x4){0.f, 0.f, 0.f, 0.f};

    auto stage = [&](int buf, int kt) {
        const int k0 = kt * 32;
        unsigned short* base = &smem[buf * 8192];
        #pragma unroll
        for (int q = 0; q < 4; ++q) {
            const int c = wid * 4 + q;
            const unsigned short* g = (c < 8)
                ? A + (size_t)(m0 + c * 16 + lrow) * K + k0 + lcol
                : BT + (size_t)(n0 + (c - 8) * 16 + lrow) * K + k0 + lcol;
            gload16(g, base + c * 512);
        }
    };

    const int nkt = K >> 5;
    stage(0, 0);
    __syncthreads();

    for (int kt = 0; kt < nkt; ++kt) {
        const int cur = kt & 1;
        if (kt + 1 < nkt) stage(cur ^ 1, kt + 1);

        const unsigned short* sb = &smem[cur * 8192];
        bf16x8 af[4], bf[4];
        #pragma unroll
        for (int mi = 0; mi < 4; ++mi)
            af[mi] = *reinterpret_cast<const bf16x8*>(
                &sb[(wm * 64 + mi * 16 + fr) * 32 + kg * 8]);
        #pragma unroll
        for (int ni = 0; ni < 4; ++ni)
            bf[ni] = *reinterpret_cast<const bf16x8*>(
                &sb[4096 + (wn * 64 + ni * 16 + fr) * 32 + kg * 8]);
        #pragma unroll
        for (int mi = 0; mi < 4; ++mi)
            #pragma unroll
            for (int ni = 0; ni < 4; ++ni)
                acc[mi][ni] = __builtin_amdgcn_mfma_f32_16x16x32_bf16(
                    af[mi], bf[ni], acc[mi][ni], 0, 0, 0);
        __syncthreads();
    }

    #pragma unroll
    for (int ni = 0; ni < 4; ++ni) {
        const int n = n0 + wn * 64 + ni * 16 + fr;
        const float bv = bias ? bias[n] : 0.f;
        #pragma unroll
        for (int mi = 0; mi < 4; ++mi)
            #pragma unroll
            for (int r = 0; r < 4; ++r) {
                const int m = m0 + wm * 64 + mi * 16 + kg * 4 + r;
                C[(size_t)m * N + n] = acc[mi][ni][r] + bv;
            }
    }
}

// ---------------------------------------------------------------------------
// Tree level mega-GEMM (double-buffered): G = h_c @ [U_iou | U_f].
// Epilogue scatters to giou (atomic) / fcs (f=sig(G+xf[parent]), atomic).
// ---------------------------------------------------------------------------
__global__ __launch_bounds__(256)
void tree_gemm(const unsigned short* __restrict__ hTb,
               const unsigned short* __restrict__ UcombT,  // [2048][512]
               const float* __restrict__ xg,               // [N][2048]
               const float* __restrict__ cT,               // [N][512]
               const int* __restrict__ parent,
               int cstart, int pstart,
               float* __restrict__ giou,                   // [PER][1536]
               float* __restrict__ fcs)                    // [PER][512]
{
    constexpr int H = 512, N4H = 2048, G3H = 1536;
    const int m0 = blockIdx.x * 64, n0 = blockIdx.y * 128;
    const int tid = (int)threadIdx.x, lane = tid & 63, wid = tid >> 6;
    const int wm = wid >> 1, wn = wid & 1;
    const int fr = lane & 15, kg = lane >> 4;
    const int lrow = lane >> 2, lcol = (lane & 3) * 8;

    __shared__ unsigned short smem[2 * 6144];

    f32x4 acc[2][4];
    #pragma unroll
    for (int i = 0; i < 2; ++i)
        #pragma unroll
        for (int j = 0; j < 4; ++j)
            acc[i][j] = (f32x4){0.f, 0.f, 0.f, 0.f};

    auto stage = [&](int buf, int kt) {
        const int k0 = kt * 32;
        unsigned short* base = &smem[buf * 6144];
        #pragma unroll
        for (int q = 0; q < 3; ++q) {
            const int c = wid * 3 + q;   // 12 chunks
            const unsigned short* g = (c < 4)
                ? hTb + (size_t)(cstart + m0 + c * 16 + lrow) * H + k0 + lcol
                : UcombT + (size_t)(n0 + (c - 4) * 16 + lrow) * H + k0 + lcol;
            gload16(g, base + c * 512);
        }
    };

    constexpr int nkt = H / 32;  // 16
    stage(0, 0);
    __syncthreads();

    for (int kt = 0; kt < nkt; ++kt) {
        const int cur = kt & 1;
        if (kt + 1 < nkt) stage(cur ^ 1, kt + 1);

        const unsigned short* sb = &smem[cur * 6144];
        bf16x8 af[2], bf[4];
        #pragma unroll
        for (int mi = 0; mi < 2; ++mi)
            af[mi] = *reinterpret_cast<const bf16x8*>(
                &sb[(wm * 32 + mi * 16 + fr) * 32 + kg * 8]);
        #pragma unroll
        for (int ni = 0; ni < 4; ++ni)
            bf[ni] = *reinterpret_cast<const bf16x8*>(
                &sb[2048 + (wn * 64 + ni * 16 + fr) * 32 + kg * 8]);
        #pragma unroll
        for (int mi = 0; mi < 2; ++mi)
            #pragma unroll
            for (int ni = 0; ni < 4; ++ni)
                acc[mi][ni] = __builtin_amdgcn_mfma_f32_16x16x32_bf16(
                    af[mi], bf[ni], acc[mi][ni], 0, 0, 0);
        __syncthreads();
    }

    if (n0 < G3H) {
        #pragma unroll
        for (int mi = 0; mi < 2; ++mi)
            #pragma unroll
            for (int r = 0; r < 4; ++r) {
                const int m = m0 + wm * 32 + mi * 16 + kg * 4 + r;
                const int p = parent[cstart + m] - pstart;
                #pragma unroll
                for (int ni = 0; ni < 4; ++ni) {
                    const int n = n0 + wn * 64 + ni * 16 + fr;
                    atomicAdd(&giou[(size_t)p * G3H + n], acc[mi][ni][r]);
                }
            }
    } else {
        #pragma unroll
        for (int mi = 0; mi < 2; ++mi)
            #pragma unroll
            for (int r = 0; r < 4; ++r) {
                const int m = m0 + wm * 32 + mi * 16 + kg * 4 + r;
                const int child = cstart + m;
                const int p = parent[child];
                #pragma unroll
                for (int ni = 0; ni < 4; ++ni) {
                    const int jf = n0 + wn * 64 + ni * 16 + fr - G3H;
                    const float f = sigf(acc[mi][ni][r] + xg[(size_t)p * N4H + G3H + jf]);
                    atomicAdd(&fcs[(size_t)(p - pstart) * H + jf],
                              f * cT[(size_t)child * H + jf]);
                }
            }
    }
}

// ---------------------------------------------------------------------------
// level update; also re-zeros exactly the giou/fcs slots this thread read
// (exclusive ownership) so the next level needs no memset.
// ---------------------------------------------------------------------------
__global__ void level_update(const float* __restrict__ xg,
                             float* __restrict__ giou,
                             float* __restrict__ fcs,
                             float* __restrict__ cT, float* __restrict__ hT,
                             unsigned short* __restrict__ hb, int pstart)
{
    constexpr int H = 512, N4H = 2048, G3H = 1536;
    const int idx = blockIdx.x * blockDim.x + threadIdx.x;  // PER*H exact
    const int pi = idx >> 9, j = idx & (H - 1);
    const int p = pstart + pi;
    const size_t xb4 = (size_t)p * N4H;
    const size_t gb = (size_t)pi * G3H;
    const float ig = sigf(xg[xb4 + j] + giou[gb + j]);
    const float og = sigf(xg[xb4 + H + j] + giou[gb + H + j]);
    const float ug = tanhf(xg[xb4 + 2 * H + j] + giou[gb + 2 * H + j]);
    const float cn = ig * ug + fcs[idx];
    const float hn = og * tanhf(cn);
    const size_t off = (size_t)p * H + j;
    cT[off] = cn;
    hT[off] = hn;
    hb[off] = f2bf(hn);
    // re-zero for next level (exclusive slots)
    giou[gb + j] = 0.f;
    giou[gb + H + j] = 0.f;
    giou[gb + 2 * H + j] = 0.f;
    fcs[idx] = 0.f;
}

__global__ void gather_out_kernel(const float* __restrict__ c,
                                  const float* __restrict__ h,
                                  const int* __restrict__ root_ids,
                                  int nroot, float* __restrict__ out)
{
    constexpr int H = 512;
    const int idx = blockIdx.x * blockDim.x + threadIdx.x;  // nroot*H exact
    const int t = idx >> 9, j = idx & (H - 1);
    const int rid = root_ids[t];
    out[idx] = c[(size_t)rid * H + j];
    out[(size_t)nroot * H + idx] = h[(size_t)rid * H + j];
}

// ---------------------------------------------------------------------------
extern "C" void kernel_launch(void* const* d_in, const int* in_sizes, int n_in,
                              void* d_out, int out_size, void* d_ws, size_t ws_size,
                              hipStream_t stream)
{
    const float* x_seq = (const float*)d_in[0];
    const float* W_ih  = (const float*)d_in[1];
    const float* W_hh  = (const float*)d_in[2];
    const float* b_ih  = (const float*)d_in[3];
    const float* b_hh  = (const float*)d_in[4];
    const float* Wx    = (const float*)d_in[5];
    const float* bx    = (const float*)d_in[6];
    const float* U_iou = (const float*)d_in[7];
    const float* U_f   = (const float*)d_in[8];
    const int* parent  = (const int*)d_in[9];
    const int* root_ids = (const int*)d_in[11];

    const int threeH = in_sizes[3];          // 1536
    const int H   = threeH / 3;              // 512
    const int I   = in_sizes[1] / threeH;    // 256
    const int N   = in_sizes[9];             // 8192
    const int L   = in_sizes[0] / (N * I);   // 8
    const int PER = in_sizes[11];            // 1024
    const int D   = N / PER;                 // 8

    const size_t NH = (size_t)N * H;
    const size_t PH = (size_t)PER * H;

    // ---- workspace carve-up (xb aliases xg: xb dead before xg written) ----
    char* p = (char*)d_ws;
    const size_t zone_sz = ((size_t)N * 4 * H * 4 > (size_t)N * L * I * 2)
                         ? (size_t)N * 4 * H * 4 : (size_t)N * L * I * 2;
    unsigned short* xb = (unsigned short*)p;
    float* xg = (float*)p;                       p += zone_sz;
    unsigned short* hb0 = (unsigned short*)p;    p += NH * 2;
    unsigned short* hb1 = (unsigned short*)p;    p += NH * 2;
    float* cT = (float*)p;                       p += NH * 4;
    float* hT = (float*)p;                       p += NH * 4;
    unsigned short* WihT = (unsigned short*)p;   p += (size_t)threeH * I * 2;
    unsigned short* WhhT = (unsigned short*)p;   p += (size_t)threeH * H * 2;
    unsigned short* WxT  = (unsigned short*)p;   p += (size_t)4 * H * H * 2;
    unsigned short* UcombT = (unsigned short*)p; p += (size_t)4 * H * H * 2;
    float* giou = (float*)p;                     p += PH * 3 * 4;
    float* fcs  = (float*)p;                     p += PH * 4;   // adjacent to giou
    if ((size_t)(p - (char*)d_ws) > ws_size) return;

    // ---- prep ----
    {
        const int n = N * L * I;
        cvt_f32_bf16<<<(n / 4 + 255) / 256, 256, 0, stream>>>(x_seq, xb, n);
        dim3 blk(32, 8);
        transpose_cvt<<<dim3(threeH / 32, I / 32), blk, 0, stream>>>(W_ih, WihT, I, threeH);
        transpose_cvt<<<dim3(threeH / 32, H / 32), blk, 0, stream>>>(W_hh, WhhT, H, threeH);
        transpose_cvt<<<dim3(4 * H / 32, H / 32), blk, 0, stream>>>(Wx, WxT, H, 4 * H);
        transpose_cvt<<<dim3(threeH / 32, H / 32), blk, 0, stream>>>(U_iou, UcombT, H, threeH);
        transpose_cvt<<<dim3(H / 32, H / 32), blk, 0, stream>>>(
            U_f, UcombT + (size_t)threeH * H, H, H);
    }
    hipMemsetAsync(hb0, 0, NH * 2, stream);
    hipMemsetAsync(giou, 0, PH * 4 * 4, stream);   // giou + fcs once (ws is poisoned)

    // ---- Phase 1: GRU (bf16 state ping-pong) ----
    {
        dim3 grid(N / 128, H / 64);
        for (int t = 0; t < L; ++t) {
            const unsigned short* hin = (t & 1) ? hb1 : hb0;
            unsigned short* hout = (t & 1) ? hb0 : hb1;
            gru_mfma<<<grid, 256, 0, stream>>>(xb, t, hin, hout,
                                               WihT, WhhT, b_ih, b_hh);
        }
        // L even -> enc bf16 in hb0
    }

    // ---- Phase 2: xg = enc @ Wx + bx ----
    mfma_gemm128<<<dim3(N / 128, 4 * H / 128), 256, 0, stream>>>(
        hb0, WxT, bx, xg, N, 4 * H, H);

    // ---- Phase 3: tree levels (deepest -> roots) ----
    unsigned short* hTb = hb1;  // tree h (bf16), free after GRU
    const int pw_blocks = (int)(PH / 256);

    for (int lvl = D - 1; lvl >= 0; --lvl) {
        const int pstart = lvl * PER;
        const int cstart = (lvl + 1) * PER;

        if (lvl < D - 1)
            tree_gemm<<<dim3(PER / 64, (4 * H) / 128), 256, 0, stream>>>(
                hTb, UcombT, xg, cT, parent, cstart, pstart, giou, fcs);

        level_update<<<pw_blocks, 256, 0, stream>>>(xg, giou, fcs, cT, hT,
                                                    hTb, pstart);
    }

    // ---- Phase 4: gather roots ----
    gather_out_kernel<<<pw_blocks, 256, 0, stream>>>(cT, hT, root_ids, PER,
                                                     (float*)d_out);
}

// Round 6
// 541.455 us; speedup vs baseline: 5.5367x; 1.1624x over previous
//
#include <hip/hip_runtime.h>
#include <math.h>

typedef short bf16x8 __attribute__((ext_vector_type(8)));
typedef float f32x4 __attribute__((ext_vector_type(4)));

__device__ __forceinline__ float sigf(float x) { return 1.0f / (1.0f + __expf(-x)); }

__device__ __forceinline__ unsigned short f2bf(float f) {
    union { float f; unsigned u; } v; v.f = f;
    unsigned r = (v.u + 0x7FFFu + ((v.u >> 16) & 1u)) >> 16;
    return (unsigned short)r;
}
__device__ __forceinline__ float bf2f(unsigned short u) {
    union { unsigned u; float f; } v; v.u = ((unsigned)u) << 16; return v.f;
}

// async global->LDS, 16B per lane; LDS dest = wave-uniform base + lane*16B.
__device__ __forceinline__ void gload16(const unsigned short* g, unsigned short* l) {
    __builtin_amdgcn_global_load_lds(
        (const __attribute__((address_space(1))) void*)g,
        (__attribute__((address_space(3))) void*)l, 16, 0, 0);
}

// Chunk layout: 16 rows x 32 ushorts (1 KiB). Lane i -> (row=i>>2, slot=i&3).
// Bank swizzle (both-sides): source col = (slot ^ ((row>>1)&3))*8; LDS linear;
// reads use the same XOR. Spreads quarter-wave b128 reads across 8 bank-quads.
__device__ __forceinline__ int swz(int slot, int row) {
    return (slot ^ ((row >> 1) & 3)) * 8;
}

// ---------------------------------------------------------------------------
// prep kernels
// ---------------------------------------------------------------------------
__global__ void cvt_f32_bf16(const float* __restrict__ src,
                             unsigned short* __restrict__ dst, int n)
{
    const int i = (blockIdx.x * blockDim.x + threadIdx.x) * 4;
    if (i >= n) return;
    const float4 v = *reinterpret_cast<const float4*>(src + i);
    ushort4 o;
    o.x = f2bf(v.x); o.y = f2bf(v.y); o.z = f2bf(v.z); o.w = f2bf(v.w);
    *reinterpret_cast<ushort4*>(dst + i) = o;
}

// dst[c][r] = bf16(src[r][c]); rows, cols multiples of 32
__global__ void transpose_cvt(const float* __restrict__ src,
                              unsigned short* __restrict__ dst,
                              int rows, int cols)
{
    __shared__ float tile[32][33];
    const int bc = blockIdx.x * 32, br = blockIdx.y * 32;
    const int tx = threadIdx.x, ty = threadIdx.y;  // block (32,8)
    #pragma unroll
    for (int i = 0; i < 32; i += 8)
        tile[ty + i][tx] = src[(size_t)(br + ty + i) * cols + bc + tx];
    __syncthreads();
    #pragma unroll
    for (int i = 0; i < 32; i += 8)
        dst[(size_t)(bc + ty + i) * rows + br + tx] = f2bf(tile[tx][ty + i]);
}

// ---------------------------------------------------------------------------
// Fused MFMA GRU step. 3-buffer, 3-deep counted-vmcnt pipeline.
// Tile 128 rows x 64 hidden cols; 4 waves 2x2 (wave 64x32).
// K: 8 tiles of x@Wih then 16 tiles of h@Whh (nkt=24).
// Per buffer: A[128][32] @ 0, B[3][64][32] @ 4096 (10240 ushorts). 60 KiB LDS.
// Each wave stages 5 chunks/tile -> waits vmcnt(10)/5/0.
// ---------------------------------------------------------------------------
__global__ __launch_bounds__(256)
void gru_mfma(const unsigned short* __restrict__ xb, int t,
              const unsigned short* __restrict__ hbi,
              unsigned short* __restrict__ hbo,
              const unsigned short* __restrict__ WihT,
              const unsigned short* __restrict__ WhhT,
              const float* __restrict__ b_ih, const float* __restrict__ b_hh)
{
    constexpr int I = 256, H = 512, LI = 2048;
    const int m0 = blockIdx.x * 128, j0 = blockIdx.y * 64;
    const int tid = (int)threadIdx.x, lane = tid & 63, wid = tid >> 6;
    const int wm = wid >> 1, wn = wid & 1;
    const int fr = lane & 15, kg = lane >> 4;
    const int lrow = lane >> 2;
    const int scol = swz(lane & 3, lrow);    // pre-swizzled source col (ushorts)

    __shared__ unsigned short smem[3 * 10240];

    f32x4 ar[4][2], az[4][2], an[4][2], ah[4][2];
    #pragma unroll
    for (int i = 0; i < 4; ++i)
        #pragma unroll
        for (int j = 0; j < 2; ++j) {
            ar[i][j] = (f32x4){0.f, 0.f, 0.f, 0.f};
            az[i][j] = (f32x4){0.f, 0.f, 0.f, 0.f};
            an[i][j] = (f32x4){0.f, 0.f, 0.f, 0.f};
            ah[i][j] = (f32x4){0.f, 0.f, 0.f, 0.f};
        }

    constexpr int nkt1 = I / 32;          // 8
    constexpr int nkt = (I + H) / 32;     // 24

    auto stage = [&](int buf, int kt) {
        const bool s1 = (kt < nkt1);
        const int k0 = s1 ? kt * 32 : (kt - nkt1) * 32;
        unsigned short* base = &smem[buf * 10240];
        #pragma unroll
        for (int q = 0; q < 5; ++q) {
            const int c = wid * 5 + q;     // 20 chunks of 1 KiB
            if (c < 8) {
                const int row = c * 16 + lrow;
                const unsigned short* g = s1
                    ? xb + (size_t)(m0 + row) * LI + t * I + k0 + scol
                    : hbi + (size_t)(m0 + row) * H + k0 + scol;
                gload16(g, base + c * 512);
            } else {
                const int bc = c - 8, gi = bc >> 2;
                const int row = (bc & 3) * 16 + lrow;
                const unsigned short* g = s1
                    ? WihT + (size_t)(gi * H + j0 + row) * I + k0 + scol
                    : WhhT + (size_t)(gi * H + j0 + row) * H + k0 + scol;
                gload16(g, base + c * 512);
            }
        }
    };

    stage(0, 0); stage(1, 1); stage(2, 2);
    int cur = 0;

    for (int kt = 0; kt < nkt; ++kt) {
        if (kt + 2 < nkt)      asm volatile("s_waitcnt vmcnt(10)" ::: "memory");
        else if (kt + 1 < nkt) asm volatile("s_waitcnt vmcnt(5)" ::: "memory");
        else                   asm volatile("s_waitcnt vmcnt(0)" ::: "memory");
        __builtin_amdgcn_s_barrier();

        const unsigned short* sb = &smem[cur * 10240];
        bf16x8 af[4], bfr[2], bfz[2], bfn[2];
        #pragma unroll
        for (int mi = 0; mi < 4; ++mi) {
            const int row = wm * 64 + mi * 16 + fr;
            af[mi] = *reinterpret_cast<const bf16x8*>(&sb[row * 32 + swz(kg, row)]);
        }
        #pragma unroll
        for (int ni = 0; ni < 2; ++ni) {
            const int row = wn * 32 + ni * 16 + fr;
            const int sw = swz(kg, row);   // +64/+128 rows don't change bits 1-2
            bfr[ni] = *reinterpret_cast<const bf16x8*>(&sb[4096 + row * 32 + sw]);
            bfz[ni] = *reinterpret_cast<const bf16x8*>(&sb[4096 + (64 + row) * 32 + sw]);
            bfn[ni] = *reinterpret_cast<const bf16x8*>(&sb[4096 + (128 + row) * 32 + sw]);
        }
        const bool p1 = (kt < nkt1);
        #pragma unroll
        for (int mi = 0; mi < 4; ++mi)
            #pragma unroll
            for (int ni = 0; ni < 2; ++ni) {
                ar[mi][ni] = __builtin_amdgcn_mfma_f32_16x16x32_bf16(af[mi], bfr[ni], ar[mi][ni], 0, 0, 0);
                az[mi][ni] = __builtin_amdgcn_mfma_f32_16x16x32_bf16(af[mi], bfz[ni], az[mi][ni], 0, 0, 0);
                if (p1)
                    an[mi][ni] = __builtin_amdgcn_mfma_f32_16x16x32_bf16(af[mi], bfn[ni], an[mi][ni], 0, 0, 0);
                else
                    ah[mi][ni] = __builtin_amdgcn_mfma_f32_16x16x32_bf16(af[mi], bfn[ni], ah[mi][ni], 0, 0, 0);
            }

        asm volatile("s_waitcnt lgkmcnt(0)" ::: "memory");
        __builtin_amdgcn_s_barrier();
        if (kt + 3 < nkt) stage(cur, kt + 3);
        cur = (cur == 2) ? 0 : cur + 1;
    }

    #pragma unroll
    for (int ni = 0; ni < 2; ++ni) {
        const int j = j0 + wn * 32 + ni * 16 + fr;
        const float bir = b_ih[j],         bhr = b_hh[j];
        const float biz = b_ih[H + j],     bhz = b_hh[H + j];
        const float bin = b_ih[2 * H + j], bhn = b_hh[2 * H + j];
        #pragma unroll
        for (int mi = 0; mi < 4; ++mi) {
            #pragma unroll
            for (int r = 0; r < 4; ++r) {
                const int m = m0 + wm * 64 + mi * 16 + kg * 4 + r;
                const float rg = sigf(ar[mi][ni][r] + bir + bhr);
                const float zg = sigf(az[mi][ni][r] + biz + bhz);
                const float ng = tanhf(an[mi][ni][r] + bin + rg * (ah[mi][ni][r] + bhn));
                const size_t off = (size_t)m * H + j;
                const float hv = bf2f(hbi[off]);
                hbo[off] = f2bf((1.f - zg) * ng + zg * hv);
            }
        }
    }
}

// ---------------------------------------------------------------------------
// m97-style GEMM, 3-deep pipeline: C[M][N](f32) = A(bf16) @ BT^T (+bias).
// 128x128 tile; 4 chunks/wave/tile -> waits vmcnt(8)/4/0. 48 KiB LDS.
// ---------------------------------------------------------------------------
__global__ __launch_bounds__(256)
void mfma_gemm128(const unsigned short* __restrict__ A,
                  const unsigned short* __restrict__ BT,
                  const float* __restrict__ bias,
                  float* __restrict__ C, int M, int N, int K)
{
    const int m0 = blockIdx.x * 128, n0 = blockIdx.y * 128;
    const int tid = (int)threadIdx.x, lane = tid & 63, wid = tid >> 6;
    const int wm = wid >> 1, wn = wid & 1;
    const int fr = lane & 15, kg = lane >> 4;
    const int lrow = lane >> 2;
    const int scol = swz(lane & 3, lrow);

    __shared__ unsigned short smem[3 * 8192];

    f32x4 acc[4][4];
    #pragma unroll
    for (int i = 0; i < 4; ++i)
        #pragma unroll
        for (int j = 0; j < 4; ++j)
            acc[i][j] = (f32x4){0.f, 0.f, 0.f, 0.f};

    auto stage = [&](int buf, int kt) {
        const int k0 = kt * 32;
        unsigned short* base = &smem[buf * 8192];
        #pragma unroll
        for (int q = 0; q < 4; ++q) {
            const int c = wid * 4 + q;
            const unsigned short* g = (c < 8)
                ? A + (size_t)(m0 + c * 16 + lrow) * K + k0 + scol
                : BT + (size_t)(n0 + (c - 8) * 16 + lrow) * K + k0 + scol;
            gload16(g, base + c * 512);
        }
    };

    const int nkt = K >> 5;
    stage(0, 0); stage(1, 1); stage(2, 2);
    int cur = 0;

    for (int kt = 0; kt < nkt; ++kt) {
        if (kt + 2 < nkt)      asm volatile("s_waitcnt vmcnt(8)" ::: "memory");
        else if (kt + 1 < nkt) asm volatile("s_waitcnt vmcnt(4)" ::: "memory");
        else                   asm volatile("s_waitcnt vmcnt(0)" ::: "memory");
        __builtin_amdgcn_s_barrier();

        const unsigned short* sb = &smem[cur * 8192];
        bf16x8 af[4], bf[4];
        #pragma unroll
        for (int mi = 0; mi < 4; ++mi) {
            const int row = wm * 64 + mi * 16 + fr;
            af[mi] = *reinterpret_cast<const bf16x8*>(&sb[row * 32 + swz(kg, row)]);
        }
        #pragma unroll
        for (int ni = 0; ni < 4; ++ni) {
            const int row = wn * 64 + ni * 16 + fr;
            bf[ni] = *reinterpret_cast<const bf16x8*>(&sb[4096 + row * 32 + swz(kg, row)]);
        }
        #pragma unroll
        for (int mi = 0; mi < 4; ++mi)
            #pragma unroll
            for (int ni = 0; ni < 4; ++ni)
                acc[mi][ni] = __builtin_amdgcn_mfma_f32_16x16x32_bf16(
                    af[mi], bf[ni], acc[mi][ni], 0, 0, 0);

        asm volatile("s_waitcnt lgkmcnt(0)" ::: "memory");
        __builtin_amdgcn_s_barrier();
        if (kt + 3 < nkt) stage(cur, kt + 3);
        cur = (cur == 2) ? 0 : cur + 1;
    }

    #pragma unroll
    for (int ni = 0; ni < 4; ++ni) {
        const int n = n0 + wn * 64 + ni * 16 + fr;
        const float bv = bias ? bias[n] : 0.f;
        #pragma unroll
        for (int mi = 0; mi < 4; ++mi)
            #pragma unroll
            for (int r = 0; r < 4; ++r) {
                const int m = m0 + wm * 64 + mi * 16 + kg * 4 + r;
                C[(size_t)m * N + n] = acc[mi][ni][r] + bv;
            }
    }
}

// ---------------------------------------------------------------------------
// Tree level mega-GEMM, 3-deep pipeline: G = h_c @ [U_iou | U_f].
// 64x128 tile; 3 chunks/wave/tile -> waits vmcnt(6)/3/0. 36 KiB LDS.
// Epilogue scatters to giou (atomic) / fcs (f=sig(G+xf[parent]), atomic).
// ---------------------------------------------------------------------------
__global__ __launch_bounds__(256)
void tree_gemm(const unsigned short* __restrict__ hTb,
               const unsigned short* __restrict__ UcombT,  // [2048][512]
               const float* __restrict__ xg,               // [N][2048]
               const float* __restrict__ cT,               // [N][512]
               const int* __restrict__ parent,
               int cstart, int pstart,
               float* __restrict__ giou,                   // [PER][1536]
               float* __restrict__ fcs)                    // [PER][512]
{
    constexpr int H = 512, N4H = 2048, G3H = 1536;
    const int m0 = blockIdx.x * 64, n0 = blockIdx.y * 128;
    const int tid = (int)threadIdx.x, lane = tid & 63, wid = tid >> 6;
    const int wm = wid >> 1, wn = wid & 1;
    const int fr = lane & 15, kg = lane >> 4;
    const int lrow = lane >> 2;
    const int scol = swz(lane & 3, lrow);

    __shared__ unsigned short smem[3 * 6144];

    f32x4 acc[2][4];
    #pragma unroll
    for (int i = 0; i < 2; ++i)
        #pragma unroll
        for (int j = 0; j < 4; ++j)
            acc[i][j] = (f32x4){0.f, 0.f, 0.f, 0.f};

    auto stage = [&](int buf, int kt) {
        const int k0 = kt * 32;
        unsigned short* base = &smem[buf * 6144];
        #pragma unroll
        for (int q = 0; q < 3; ++q) {
            const int c = wid * 3 + q;   // 12 chunks
            const unsigned short* g = (c < 4)
                ? hTb + (size_t)(cstart + m0 + c * 16 + lrow) * H + k0 + scol
                : UcombT + (size_t)(n0 + (c - 4) * 16 + lrow) * H + k0 + scol;
            gload16(g, base + c * 512);
        }
    };

    constexpr int nkt = H / 32;  // 16
    stage(0, 0); stage(1, 1); stage(2, 2);
    int cur = 0;

    for (int kt = 0; kt < nkt; ++kt) {
        if (kt + 2 < nkt)      asm volatile("s_waitcnt vmcnt(6)" ::: "memory");
        else if (kt + 1 < nkt) asm volatile("s_waitcnt vmcnt(3)" ::: "memory");
        else                   asm volatile("s_waitcnt vmcnt(0)" ::: "memory");
        __builtin_amdgcn_s_barrier();

        const unsigned short* sb = &smem[cur * 6144];
        bf16x8 af[2], bf[4];
        #pragma unroll
        for (int mi = 0; mi < 2; ++mi) {
            const int row = wm * 32 + mi * 16 + fr;
            af[mi] = *reinterpret_cast<const bf16x8*>(&sb[row * 32 + swz(kg, row)]);
        }
        #pragma unroll
        for (int ni = 0; ni < 4; ++ni) {
            const int row = wn * 64 + ni * 16 + fr;
            bf[ni] = *reinterpret_cast<const bf16x8*>(&sb[2048 + row * 32 + swz(kg, row)]);
        }
        #pragma unroll
        for (int mi = 0; mi < 2; ++mi)
            #pragma unroll
            for (int ni = 0; ni < 4; ++ni)
                acc[mi][ni] = __builtin_amdgcn_mfma_f32_16x16x32_bf16(
                    af[mi], bf[ni], acc[mi][ni], 0, 0, 0);

        asm volatile("s_waitcnt lgkmcnt(0)" ::: "memory");
        __builtin_amdgcn_s_barrier();
        if (kt + 3 < nkt) stage(cur, kt + 3);
        cur = (cur == 2) ? 0 : cur + 1;
    }

    if (n0 < G3H) {
        #pragma unroll
        for (int mi = 0; mi < 2; ++mi)
            #pragma unroll
            for (int r = 0; r < 4; ++r) {
                const int m = m0 + wm * 32 + mi * 16 + kg * 4 + r;
                const int p = parent[cstart + m] - pstart;
                #pragma unroll
                for (int ni = 0; ni < 4; ++ni) {
                    const int n = n0 + wn * 64 + ni * 16 + fr;
                    atomicAdd(&giou[(size_t)p * G3H + n], acc[mi][ni][r]);
                }
            }
    } else {
        #pragma unroll
        for (int mi = 0; mi < 2; ++mi)
            #pragma unroll
            for (int r = 0; r < 4; ++r) {
                const int m = m0 + wm * 32 + mi * 16 + kg * 4 + r;
                const int child = cstart + m;
                const int p = parent[child];
                #pragma unroll
                for (int ni = 0; ni < 4; ++ni) {
                    const int jf = n0 + wn * 64 + ni * 16 + fr - G3H;
                    const float f = sigf(acc[mi][ni][r] + xg[(size_t)p * N4H + G3H + jf]);
                    atomicAdd(&fcs[(size_t)(p - pstart) * H + jf],
                              f * cT[(size_t)child * H + jf]);
                }
            }
    }
}

// ---------------------------------------------------------------------------
// level update; re-zeros exactly the giou/fcs slots it read (exclusive
// ownership) so no per-level memset is needed.
// ---------------------------------------------------------------------------
__global__ void level_update(const float* __restrict__ xg,
                             float* __restrict__ giou,
                             float* __restrict__ fcs,
                             float* __restrict__ cT, float* __restrict__ hT,
                             unsigned short* __restrict__ hb, int pstart)
{
    constexpr int H = 512, N4H = 2048, G3H = 1536;
    const int idx = blockIdx.x * blockDim.x + threadIdx.x;  // PER*H exact
    const int pi = idx >> 9, j = idx & (H - 1);
    const int p = pstart + pi;
    const size_t xb4 = (size_t)p * N4H;
    const size_t gb = (size_t)pi * G3H;
    const float ig = sigf(xg[xb4 + j] + giou[gb + j]);
    const float og = sigf(xg[xb4 + H + j] + giou[gb + H + j]);
    const float ug = tanhf(xg[xb4 + 2 * H + j] + giou[gb + 2 * H + j]);
    const float cn = ig * ug + fcs[idx];
    const float hn = og * tanhf(cn);
    const size_t off = (size_t)p * H + j;
    cT[off] = cn;
    hT[off] = hn;
    hb[off] = f2bf(hn);
    giou[gb + j] = 0.f;
    giou[gb + H + j] = 0.f;
    giou[gb + 2 * H + j] = 0.f;
    fcs[idx] = 0.f;
}

__global__ void gather_out_kernel(const float* __restrict__ c,
                                  const float* __restrict__ h,
                                  const int* __restrict__ root_ids,
                                  int nroot, float* __restrict__ out)
{
    constexpr int H = 512;
    const int idx = blockIdx.x * blockDim.x + threadIdx.x;  // nroot*H exact
    const int t = idx >> 9, j = idx & (H - 1);
    const int rid = root_ids[t];
    out[idx] = c[(size_t)rid * H + j];
    out[(size_t)nroot * H + idx] = h[(size_t)rid * H + j];
}

// ---------------------------------------------------------------------------
extern "C" void kernel_launch(void* const* d_in, const int* in_sizes, int n_in,
                              void* d_out, int out_size, void* d_ws, size_t ws_size,
                              hipStream_t stream)
{
    const float* x_seq = (const float*)d_in[0];
    const float* W_ih  = (const float*)d_in[1];
    const float* W_hh  = (const float*)d_in[2];
    const float* b_ih  = (const float*)d_in[3];
    const float* b_hh  = (const float*)d_in[4];
    const float* Wx    = (const float*)d_in[5];
    const float* bx    = (const float*)d_in[6];
    const float* U_iou = (const float*)d_in[7];
    const float* U_f   = (const float*)d_in[8];
    const int* parent  = (const int*)d_in[9];
    const int* root_ids = (const int*)d_in[11];

    const int threeH = in_sizes[3];          // 1536
    const int H   = threeH / 3;              // 512
    const int I   = in_sizes[1] / threeH;    // 256
    const int N   = in_sizes[9];             // 8192
    const int L   = in_sizes[0] / (N * I);   // 8
    const int PER = in_sizes[11];            // 1024
    const int D   = N / PER;                 // 8

    const size_t NH = (size_t)N * H;
    const size_t PH = (size_t)PER * H;

    // ---- workspace carve-up (xb aliases xg: xb dead before xg written) ----
    char* p = (char*)d_ws;
    const size_t zone_sz = ((size_t)N * 4 * H * 4 > (size_t)N * L * I * 2)
                         ? (size_t)N * 4 * H * 4 : (size_t)N * L * I * 2;
    unsigned short* xb = (unsigned short*)p;
    float* xg = (float*)p;                       p += zone_sz;
    unsigned short* hb0 = (unsigned short*)p;    p += NH * 2;
    unsigned short* hb1 = (unsigned short*)p;    p += NH * 2;
    float* cT = (float*)p;                       p += NH * 4;
    float* hT = (float*)p;                       p += NH * 4;
    unsigned short* WihT = (unsigned short*)p;   p += (size_t)threeH * I * 2;
    unsigned short* WhhT = (unsigned short*)p;   p += (size_t)threeH * H * 2;
    unsigned short* WxT  = (unsigned short*)p;   p += (size_t)4 * H * H * 2;
    unsigned short* UcombT = (unsigned short*)p; p += (size_t)4 * H * H * 2;
    float* giou = (float*)p;                     p += PH * 3 * 4;
    float* fcs  = (float*)p;                     p += PH * 4;   // adjacent to giou
    if ((size_t)(p - (char*)d_ws) > ws_size) return;

    // ---- prep ----
    {
        const int n = N * L * I;
        cvt_f32_bf16<<<(n / 4 + 255) / 256, 256, 0, stream>>>(x_seq, xb, n);
        dim3 blk(32, 8);
        transpose_cvt<<<dim3(threeH / 32, I / 32), blk, 0, stream>>>(W_ih, WihT, I, threeH);
        transpose_cvt<<<dim3(threeH / 32, H / 32), blk, 0, stream>>>(W_hh, WhhT, H, threeH);
        transpose_cvt<<<dim3(4 * H / 32, H / 32), blk, 0, stream>>>(Wx, WxT, H, 4 * H);
        transpose_cvt<<<dim3(threeH / 32, H / 32), blk, 0, stream>>>(U_iou, UcombT, H, threeH);
        transpose_cvt<<<dim3(H / 32, H / 32), blk, 0, stream>>>(
            U_f, UcombT + (size_t)threeH * H, H, H);
    }
    hipMemsetAsync(hb0, 0, NH * 2, stream);
    hipMemsetAsync(giou, 0, PH * 4 * 4, stream);   // giou + fcs once

    // ---- Phase 1: GRU (bf16 state ping-pong) ----
    {
        dim3 grid(N / 128, H / 64);
        for (int t = 0; t < L; ++t) {
            const unsigned short* hin = (t & 1) ? hb1 : hb0;
            unsigned short* hout = (t & 1) ? hb0 : hb1;
            gru_mfma<<<grid, 256, 0, stream>>>(xb, t, hin, hout,
                                               WihT, WhhT, b_ih, b_hh);
        }
        // L even -> enc bf16 in hb0
    }

    // ---- Phase 2: xg = enc @ Wx + bx ----
    mfma_gemm128<<<dim3(N / 128, 4 * H / 128), 256, 0, stream>>>(
        hb0, WxT, bx, xg, N, 4 * H, H);

    // ---- Phase 3: tree levels (deepest -> roots) ----
    unsigned short* hTb = hb1;  // tree h (bf16), free after GRU
    const int pw_blocks = (int)(PH / 256);

    for (int lvl = D - 1; lvl >= 0; --lvl) {
        const int pstart = lvl * PER;
        const int cstart = (lvl + 1) * PER;

        if (lvl < D - 1)
            tree_gemm<<<dim3(PER / 64, (4 * H) / 128), 256, 0, stream>>>(
                hTb, UcombT, xg, cT, parent, cstart, pstart, giou, fcs);

        level_update<<<pw_blocks, 256, 0, stream>>>(xg, giou, fcs, cT, hT,
                                                    hTb, pstart);
    }

    // ---- Phase 4: gather roots ----
    gather_out_kernel<<<pw_blocks, 256, 0, stream>>>(cT, hT, root_ids, PER,
                                                     (float*)d_out);
}